// Round 7
// baseline (181.270 us; speedup 1.0000x reference)
//
#include <hip/hip_runtime.h>

#define L_ATT 2304
// SCALE * log2(e): softmax via exp2 is mathematically identical
#define QSCALE_LOG2E 0.5100695712f

using bh8 = __attribute__((ext_vector_type(8))) short;  // 8 bf16 (4 VGPRs)
using f4  = __attribute__((ext_vector_type(4))) float;  // 4 fp32 acc

#if __has_builtin(__builtin_amdgcn_exp2f)
#define EXP2(x) __builtin_amdgcn_exp2f(x)
#else
#define EXP2(x) exp2f(x)
#endif

__device__ inline short f2b(float f) {   // RNE
    union { float f; unsigned u; } c; c.f = f;
    unsigned r = (c.u + 0x7FFFu + ((c.u >> 16) & 1u)) >> 16;
    return (short)r;
}
// pack hi16(lo), hi16(hi) -> one dword (two bf16, truncation; bias cancels in softmax)
__device__ inline int packhi(float lo, float hi) {
    return (int)__builtin_amdgcn_perm(__float_as_uint(hi), __float_as_uint(lo), 0x07060302u);
}

// ---------------------------------------------------------------------------
// Weight conversion: qkv_w (192x512) + res_w (512x64) fp32->bf16 natural;
// pos_w (64x64x9) -> wqp[q][oc][ic] bf16. grid 272 x 256.
// ---------------------------------------------------------------------------
__global__ __launch_bounds__(256) void wcvt_kernel(
    const float* __restrict__ qkv_w, const float* __restrict__ res_w,
    const float* __restrict__ pos_w,
    short* __restrict__ wqb, short* __restrict__ reswb, short* __restrict__ wqp)
{
    int j = blockIdx.x * 256 + threadIdx.x;
    if (j < 24576) {
        float4 v = ((const float4*)qkv_w)[j];
        short4 o = { f2b(v.x), f2b(v.y), f2b(v.z), f2b(v.w) };
        *(short4*)(wqb + (size_t)j * 4) = o;
    } else if (j < 32768) {
        int idx = j - 24576;
        float4 v = ((const float4*)res_w)[idx];
        short4 o = { f2b(v.x), f2b(v.y), f2b(v.z), f2b(v.w) };
        *(short4*)(reswb + (size_t)idx * 4) = o;
    } else {
        int e = j - 32768;                 // e = q*4096 + (oc*64+ic)
        wqp[e] = f2b(pos_w[(size_t)(e & 4095) * 9 + (e >> 12)]);
    }
}

// ---------------------------------------------------------------------------
// x [n][512][2304] fp32 -> xt [n][2304][512] bf16 (LDS tile transpose).
// grid (36, 8, 4)
// ---------------------------------------------------------------------------
__global__ __launch_bounds__(256) void xt_kernel(
    const float* __restrict__ x, short* __restrict__ xt)
{
    const int l0 = blockIdx.x * 64, k0 = blockIdx.y * 64, n = blockIdx.z;
    __shared__ float s[64][68];
    const int tr = threadIdx.x >> 4, tc4 = (threadIdx.x & 15) * 4;
    const float* xp = x + ((size_t)n * 512 + k0) * L_ATT + l0;
#pragma unroll
    for (int r = 0; r < 4; ++r)
        *(float4*)&s[tr + r * 16][tc4] =
            *(const float4*)(xp + (size_t)(tr + r * 16) * L_ATT + tc4);
    __syncthreads();
    short* op = xt + ((size_t)n * L_ATT + l0) * 512 + k0;
#pragma unroll
    for (int r = 0; r < 4; ++r) {
        int l = tr + r * 16;
        short4 o = { f2b(s[tc4 + 0][l]), f2b(s[tc4 + 1][l]),
                     f2b(s[tc4 + 2][l]), f2b(s[tc4 + 3][l]) };
        *(short4*)(op + (size_t)l * 512 + tc4) = o;
    }
}

// ---------------------------------------------------------------------------
// qkv 1x1 conv as MFMA GEMM, fragments straight from global.
// Block 512 = 8 waves: wave -> (oc-strip = w>>1, l-half = w&1), so each wave
// does 2 l-frags x 16 oc: per k-step only 3 VMEM loads (1 A + 2 B).
// Flat grid 432, XCD-swizzled (code = ltile + 36*n shares g&7).
// Epilogue: q (x QSCALE_LOG2E) + k -> qkt; v -> vt + vle.
// ---------------------------------------------------------------------------
__global__ __launch_bounds__(512) void qkv_kernel(
    const short* __restrict__ xt, const short* __restrict__ wqb,
    const float* __restrict__ qkv_b, short* __restrict__ qkt,
    short* __restrict__ vt, short* __restrict__ vle)
{
    const int g = blockIdx.x;              // 432 = 8 * 54
    const int xcd = g & 7, rr = g >> 3;    // rr < 54
    const int y = rr % 3, grp = rr / 3;    // grp < 18
    const int code = grp * 8 + xcd;        // = ltile + 36*n, < 144
    const int l0 = (code % 36) * 64, oc0 = y * 64, n = code / 36;

    const int lane = threadIdx.x & 63, wave = threadIdx.x >> 6;  // 0..7
    const int col = lane & 15, quad = lane >> 4;
    const int ocs = wave >> 1, lh = wave & 1;
    const int ocb = oc0 + ocs * 16;

    f4 acc[2];
    acc[0] = (f4){0.f, 0.f, 0.f, 0.f};
    acc[1] = (f4){0.f, 0.f, 0.f, 0.f};

    const short* arow = wqb + (size_t)(ocb + col) * 512 + quad * 8;
    const short* brow = xt + ((size_t)n * L_ATT + l0 + lh * 32 + col) * 512 + quad * 8;

#pragma unroll 4
    for (int k0 = 0; k0 < 512; k0 += 32) {
        bh8 af = *(const bh8*)(arow + k0);
        bh8 b0 = *(const bh8*)(brow + k0);
        bh8 b1 = *(const bh8*)(brow + (size_t)16 * 512 + k0);
        acc[0] = __builtin_amdgcn_mfma_f32_16x16x32_bf16(af, b0, acc[0], 0, 0, 0);
        acc[1] = __builtin_amdgcn_mfma_f32_16x16x32_bf16(af, b1, acc[1], 0, 0, 0);
    }

#pragma unroll
    for (int nt = 0; nt < 2; ++nt) {
        int l = l0 + lh * 32 + nt * 16 + col;
#pragma unroll
        for (int reg = 0; reg < 4; ++reg) {
            int oc = ocb + quad * 4 + reg;
            float v = acc[nt][reg] + qkv_b[oc];
            int h = oc / 24;
            int r = oc - h * 24;
            if (r < 16) {
                float sv = (r < 8) ? v * QSCALE_LOG2E : v;
                qkt[(((size_t)(n * 8 + h)) * L_ATT + l) * 16 + r] = f2b(sv);
            } else {
                int d = r - 16;
                short bv = f2b(v);
                vt[(((size_t)(n * 8 + h)) * 8 + d) * L_ATT + l] = bv;
                vle[((size_t)n * L_ATT + l) * 64 + h * 8 + d] = bv;
            }
        }
    }
}

// ---------------------------------------------------------------------------
// Flash attention, zero LDS, split-K(2): block = 64 queries x 1152 keys.
// Writes PARTIAL numerator O^T + partial lsum (no divide); combine_kernel
// finishes. Flat grid 2304, XCD-swizzled: h = g&7 keeps each (n,h)'s K/V
// slice on one XCD's L2. Register-double-buffered K/V prefetch.
// S^T = K.Q^T with permuted key map; exp2 (q pre-scaled by log2 e);
// P packed via v_perm; PV: O^T = V.P^T, ones-row d=8 gives lsum free.
// ---------------------------------------------------------------------------
__global__ __launch_bounds__(256) void attn_kernel(
    const short* __restrict__ qkt, const short* __restrict__ vt,
    float* __restrict__ pnum, float* __restrict__ pls)
{
    const int g = blockIdx.x;              // 2304 = 8 * 288
    const int h = g & 7, r = g >> 3;       // r < 288
    const int n = r / 72;
    const int rem = r - n * 72;
    const int qt = rem >> 1, half = rem & 1;
    const int q0 = qt * 64;
    const int kbase = half * 1152;
    const int slice = n * 8 + h;

    const int lane = threadIdx.x & 63, wave = threadIdx.x >> 6;
    const int col = lane & 15, quad = lane >> 4;

    const short* qk = qkt + (size_t)slice * L_ATT * 16;
    const short* vb = vt + (size_t)slice * 8 * L_ATT;

    bh8 zero8 = {0, 0, 0, 0, 0, 0, 0, 0};
    bh8 qf = zero8;
    if (quad == 0)
        qf = *(const bh8*)(qk + ((size_t)(q0 + wave * 16 + col)) * 16);

    bh8 onef;
#pragma unroll
    for (int j = 0; j < 8; ++j) onef[j] = (short)0x3F80;  // bf16 1.0

    // K fragment pointers: mfma nt reads key = kt + 32*(nt>>1)+4*(nt&1)+koff(col)
    const int koff = 8 * (col >> 2) + (col & 3);
    const short* kp[4];
#pragma unroll
    for (int nt = 0; nt < 4; ++nt)
        kp[nt] = qk + (size_t)(32 * (nt >> 1) + 4 * (nt & 1) + koff) * 16 + 8;

    // V fragment pointers (A operand of PV): row d=col, keys ks*32+quad*8+j
    const short* vp[2];
#pragma unroll
    for (int ks = 0; ks < 2; ++ks)
        vp[ks] = vb + (size_t)(col & 7) * L_ATT + ks * 32 + quad * 8;

    // double-buffered fragments; masked lanes initialized ONCE (stay 0 / ones)
    bh8 kb[2][4], vbuf[2][2];
#pragma unroll
    for (int p = 0; p < 2; ++p) {
#pragma unroll
        for (int nt = 0; nt < 4; ++nt) kb[p][nt] = zero8;
        bh8 vinit = (col == 8) ? onef : zero8;
        vbuf[p][0] = vinit; vbuf[p][1] = vinit;
    }

    // preload tile 0 of this half
    if (quad == 0) {
#pragma unroll
        for (int nt = 0; nt < 4; ++nt)
            kb[0][nt] = *(const bh8*)(kp[nt] + (size_t)kbase * 16);
    }
    if (col < 8) {
#pragma unroll
        for (int ks = 0; ks < 2; ++ks)
            vbuf[0][ks] = *(const bh8*)(vp[ks] + kbase);
    }

    f4 oacc = (f4){0.f, 0.f, 0.f, 0.f};

#pragma unroll 2
    for (int kt = kbase; kt < kbase + 1152; kt += 64) {
        const int p = (kt >> 6) & 1, pn = p ^ 1;
        // prefetch next tile (final overrun <5KB, stays inside workspace)
        if (quad == 0) {
#pragma unroll
            for (int nt = 0; nt < 4; ++nt)
                kb[pn][nt] = *(const bh8*)(kp[nt] + (size_t)(kt + 64) * 16);
        }
        if (col < 8) {
#pragma unroll
            for (int ks = 0; ks < 2; ++ks)
                vbuf[pn][ks] = *(const bh8*)(vp[ks] + kt + 64);
        }
        // compute on buffer p
        f4 s[4];
#pragma unroll
        for (int nt = 0; nt < 4; ++nt) {
            f4 z = (f4){0.f, 0.f, 0.f, 0.f};
            s[nt] = __builtin_amdgcn_mfma_f32_16x16x32_bf16(kb[p][nt], qf, z, 0, 0, 0);
        }
        float e[4][4];
#pragma unroll
        for (int nt = 0; nt < 4; ++nt)
#pragma unroll
            for (int reg = 0; reg < 4; ++reg)
                e[nt][reg] = EXP2(s[nt][reg]);
#pragma unroll
        for (int ks = 0; ks < 2; ++ks) {
            union { int i[4]; bh8 v; } pu;
            pu.i[0] = packhi(e[2 * ks][0],     e[2 * ks][1]);
            pu.i[1] = packhi(e[2 * ks][2],     e[2 * ks][3]);
            pu.i[2] = packhi(e[2 * ks + 1][0], e[2 * ks + 1][1]);
            pu.i[3] = packhi(e[2 * ks + 1][2], e[2 * ks + 1][3]);
            oacc = __builtin_amdgcn_mfma_f32_16x16x32_bf16(vbuf[p][ks], pu.v, oacc, 0, 0, 0);
        }
    }

    // O^T rows: quad0 -> d0..3, quad1 -> d4..7, quad2/reg0 -> lsum (row 8).
    const int q = q0 + wave * 16 + col;
    if (quad < 2) {
        float4 o = { oacc[0], oacc[1], oacc[2], oacc[3] };
        *(float4*)(pnum + (((size_t)(slice * 2 + half)) * L_ATT + q) * 8 + quad * 4) = o;
    } else if (quad == 2) {
        pls[((size_t)(slice * 2 + half)) * L_ATT + q] = oacc[0];
    }
}

// ---------------------------------------------------------------------------
// Combine split-K partials: t32[n][q][h*8+d] = (num0+num1)/(ls0+ls1).
// grid 288 x 256 (73728 threads = 32 slices x 2304 q).
// ---------------------------------------------------------------------------
__global__ __launch_bounds__(256) void combine_kernel(
    const float* __restrict__ pnum, const float* __restrict__ pls,
    float* __restrict__ t32)
{
    int j = blockIdx.x * 256 + threadIdx.x;
    int slice = j / L_ATT, q = j - slice * L_ATT;
    const float4* n0 = (const float4*)(pnum + (((size_t)(slice * 2 + 0)) * L_ATT + q) * 8);
    const float4* n1 = (const float4*)(pnum + (((size_t)(slice * 2 + 1)) * L_ATT + q) * 8);
    float ls = pls[((size_t)(slice * 2 + 0)) * L_ATT + q]
             + pls[((size_t)(slice * 2 + 1)) * L_ATT + q];
    float inv = 1.0f / ls;
    float4 a0 = n0[0], a1 = n0[1], b0 = n1[0], b1 = n1[1];
    float4 o0 = { (a0.x + b0.x) * inv, (a0.y + b0.y) * inv,
                  (a0.z + b0.z) * inv, (a0.w + b0.w) * inv };
    float4 o1 = { (a1.x + b1.x) * inv, (a1.y + b1.y) * inv,
                  (a1.z + b1.z) * inv, (a1.w + b1.w) * inv };
    int n = slice >> 3, h = slice & 7;
    float* dst = t32 + ((size_t)n * L_ATT + q) * 64 + h * 8;
    *(float4*)dst = o0;
    *(float4*)(dst + 4) = o1;
}

// ---------------------------------------------------------------------------
// 3x3 SAME pos-conv as MFMA implicit GEMM: 9 shifted K=64 GEMMs, no LDS.
// One wave per block, 16 l x 64 oc. grid (144, 4), block 64.
// ---------------------------------------------------------------------------
__global__ __launch_bounds__(64) void posconv_kernel(
    const short* __restrict__ vle, const short* __restrict__ wqp,
    const float* __restrict__ pbias, const float* __restrict__ t32,
    short* __restrict__ tbh)
{
    const int n = blockIdx.y;
    const int lane = threadIdx.x;
    const int l0 = blockIdx.x * 16;
    const int col = lane & 15, quad = lane >> 4;

    const int la = l0 + col;                 // A-row this lane feeds
    const int ya = la / 48, xa = la - ya * 48;

    f4 acc[4];
#pragma unroll
    for (int t = 0; t < 4; ++t) acc[t] = (f4){0.f, 0.f, 0.f, 0.f};

    const short* vbase = vle + (size_t)n * L_ATT * 64;

#pragma unroll
    for (int q = 0; q < 9; ++q) {
        const int dy = q / 3 - 1, dx = q - (q / 3) * 3 - 1;
        const bool valid = ((unsigned)(ya + dy) < 48u) && ((unsigned)(xa + dx) < 48u);
        const short* ap = vbase + (size_t)(la + dy * 48 + dx) * 64 + quad * 8;
#pragma unroll
        for (int ks = 0; ks < 2; ++ks) {
            bh8 af = {0, 0, 0, 0, 0, 0, 0, 0};
            if (valid) af = *(const bh8*)(ap + ks * 32);
#pragma unroll
            for (int t = 0; t < 4; ++t) {
                bh8 bf = *(const bh8*)(wqp + ((size_t)q * 64 + t * 16 + col) * 64
                                       + ks * 32 + quad * 8);
                acc[t] = __builtin_amdgcn_mfma_f32_16x16x32_bf16(af, bf, acc[t], 0, 0, 0);
            }
        }
    }

    const float* tp = t32 + (size_t)n * L_ATT * 64;
    short* op = tbh + (size_t)n * L_ATT * 64;
#pragma unroll
    for (int t = 0; t < 4; ++t) {
        int oc = t * 16 + col;
        float bb = pbias[oc];
#pragma unroll
        for (int reg = 0; reg < 4; ++reg) {
            int l = l0 + quad * 4 + reg;
            size_t idx = (size_t)l * 64 + oc;
            op[idx] = f2b(acc[t][reg] + tp[idx] + bb);
        }
    }
}

// ---------------------------------------------------------------------------
// res 1x1 conv: out[n][oc][l], K=64, fragments direct from global.
// Flat grid 1152, XCD-swizzled: the 8 oc-blocks sharing a tbh B-tile
// (code = ltile + 36*n) share g%8 -> same XCD L2.
// ---------------------------------------------------------------------------
__global__ __launch_bounds__(256) void res_kernel(
    const short* __restrict__ tbh, const short* __restrict__ reswb,
    const float* __restrict__ res_b, float* __restrict__ out)
{
    const int g = blockIdx.x;              // 1152 = 8 * 144
    const int xcd = g & 7, rr = g >> 3;    // rr < 144
    const int y = rr & 7, grp = rr >> 3;   // grp < 18
    const int code = grp * 8 + xcd;        // < 144
    const int l0 = (code % 36) * 64, oc0 = y * 64, n = code / 36;

    const int lane = threadIdx.x & 63, wave = threadIdx.x >> 6;
    const int col = lane & 15, quad = lane >> 4;
    const int ocb = oc0 + wave * 16;

    f4 acc[4];
#pragma unroll
    for (int nt = 0; nt < 4; ++nt) acc[nt] = (f4){0.f, 0.f, 0.f, 0.f};

#pragma unroll
    for (int ks = 0; ks < 2; ++ks) {
        bh8 af = *(const bh8*)(reswb + (size_t)(ocb + col) * 64 + ks * 32 + quad * 8);
#pragma unroll
        for (int nt = 0; nt < 4; ++nt) {
            bh8 bf = *(const bh8*)(tbh + ((size_t)n * L_ATT + l0 + nt * 16 + col) * 64
                                   + ks * 32 + quad * 8);
            acc[nt] = __builtin_amdgcn_mfma_f32_16x16x32_bf16(af, bf, acc[nt], 0, 0, 0);
        }
    }

#pragma unroll
    for (int nt = 0; nt < 4; ++nt) {
        int l = l0 + nt * 16 + col;
#pragma unroll
        for (int reg = 0; reg < 4; ++reg) {
            int oc = ocb + quad * 4 + reg;
            out[((size_t)n * 512 + oc) * L_ATT + l] = acc[nt][reg] + res_b[oc];
        }
    }
}

// ---------------------------------------------------------------------------
extern "C" void kernel_launch(void* const* d_in, const int* in_sizes, int n_in,
                              void* d_out, int out_size, void* d_ws, size_t ws_size,
                              hipStream_t stream)
{
    const float* x      = (const float*)d_in[0];
    const float* qkv_w  = (const float*)d_in[1];
    const float* qkv_b  = (const float*)d_in[2];
    const float* pos_w  = (const float*)d_in[3];
    const float* pos_b  = (const float*)d_in[4];
    const float* res_w  = (const float*)d_in[5];
    const float* res_b  = (const float*)d_in[6];
    float* out = (float*)d_out;

    char* ws = (char*)d_ws;
    short* xt    = (short*)(ws);                    //  9,437,184 B: [4][2304][512]
    short* qkt   = (short*)(ws + 9437184);          //  2,359,296 B: [4][8][2304][16]
    short* vt    = (short*)(ws + 11796480);         //  1,179,648 B: [4][8][8][2304]
    short* tbh   = (short*)(ws + 12976128);         //  1,179,648 B: [4][2304][64]
    short* wqb   = (short*)(ws + 14155776);         //    196,608 B: [192][512]
    short* reswb = (short*)(ws + 14352384);         //     65,536 B: [512][64]
    short* vle   = (short*)(ws + 14417920);         //  1,179,648 B: [4][2304][64]
    short* wqp   = (short*)(ws + 15597568);         //     73,728 B: [9][64][64]
    float* pls   = (float*)(ws + 15671296);         //    589,824 B: [32][2][2304]
    // split-K partial numerators REUSE the xt region (dead after qkv_kernel):
    float* pnum  = (float*)ws;                      //  9,437,184 B: [32][2][2304][8]
    float* t32   = (float*)d_out;                   // scratch [4][2304][64] fp32

    wcvt_kernel<<<272, 256, 0, stream>>>(qkv_w, res_w, pos_w, wqb, reswb, wqp);
    xt_kernel<<<dim3(36, 8, 4), 256, 0, stream>>>(x, xt);
    qkv_kernel<<<432, 512, 0, stream>>>(xt, wqb, qkv_b, qkt, vt, vle);
    attn_kernel<<<2304, 256, 0, stream>>>(qkt, vt, pnum, pls);
    combine_kernel<<<288, 256, 0, stream>>>(pnum, pls, t32);
    posconv_kernel<<<dim3(144, 4), 64, 0, stream>>>(vle, wqp, pos_b, t32, tbh);
    res_kernel<<<1152, 256, 0, stream>>>(tbh, reswb, res_b, out);
}

// Round 8
// 176.257 us; speedup vs baseline: 1.0284x; 1.0284x over previous
//
#include <hip/hip_runtime.h>

#define L_ATT 2304
// SCALE * log2(e): softmax via exp2 is mathematically identical
#define QSCALE_LOG2E 0.5100695712f

using bh8 = __attribute__((ext_vector_type(8))) short;  // 8 bf16 (4 VGPRs)
using f4  = __attribute__((ext_vector_type(4))) float;  // 4 fp32 acc

#if __has_builtin(__builtin_amdgcn_exp2f)
#define EXP2(x) __builtin_amdgcn_exp2f(x)
#else
#define EXP2(x) exp2f(x)
#endif

__device__ inline short f2b(float f) {   // RNE
    union { float f; unsigned u; } c; c.f = f;
    unsigned r = (c.u + 0x7FFFu + ((c.u >> 16) & 1u)) >> 16;
    return (short)r;
}
// pack hi16(lo), hi16(hi) -> one dword (two bf16, truncation; bias cancels in softmax)
__device__ inline int packhi(float lo, float hi) {
    return (int)__builtin_amdgcn_perm(__float_as_uint(hi), __float_as_uint(lo), 0x07060302u);
}

// ---------------------------------------------------------------------------
// Weight conversion + constant page. grid 273 x 256.
// qkv_w (192x512) + res_w (512x64) fp32->bf16; pos_w -> wqp[q][oc][ic];
// cpage[0..8)=bf16 1.0 (ones row), cpage[8..16)=0 (zero row).
// ---------------------------------------------------------------------------
__global__ __launch_bounds__(256) void wcvt_kernel(
    const float* __restrict__ qkv_w, const float* __restrict__ res_w,
    const float* __restrict__ pos_w,
    short* __restrict__ wqb, short* __restrict__ reswb, short* __restrict__ wqp,
    short* __restrict__ cpage)
{
    int j = blockIdx.x * 256 + threadIdx.x;
    if (j < 24576) {
        float4 v = ((const float4*)qkv_w)[j];
        short4 o = { f2b(v.x), f2b(v.y), f2b(v.z), f2b(v.w) };
        *(short4*)(wqb + (size_t)j * 4) = o;
    } else if (j < 32768) {
        int idx = j - 24576;
        float4 v = ((const float4*)res_w)[idx];
        short4 o = { f2b(v.x), f2b(v.y), f2b(v.z), f2b(v.w) };
        *(short4*)(reswb + (size_t)idx * 4) = o;
    } else if (j < 69632) {
        int e = j - 32768;                 // e = q*4096 + (oc*64+ic)
        wqp[e] = f2b(pos_w[(size_t)(e & 4095) * 9 + (e >> 12)]);
    } else if (j < 69648) {
        int e = j - 69632;
        cpage[e] = (e < 8) ? (short)0x3F80 : (short)0;
    }
}

// ---------------------------------------------------------------------------
// x [n][512][2304] fp32 -> xt [n][2304][512] bf16 (LDS tile transpose).
// grid (36, 8, 4)
// ---------------------------------------------------------------------------
__global__ __launch_bounds__(256) void xt_kernel(
    const float* __restrict__ x, short* __restrict__ xt)
{
    const int l0 = blockIdx.x * 64, k0 = blockIdx.y * 64, n = blockIdx.z;
    __shared__ float s[64][68];
    const int tr = threadIdx.x >> 4, tc4 = (threadIdx.x & 15) * 4;
    const float* xp = x + ((size_t)n * 512 + k0) * L_ATT + l0;
#pragma unroll
    for (int r = 0; r < 4; ++r)
        *(float4*)&s[tr + r * 16][tc4] =
            *(const float4*)(xp + (size_t)(tr + r * 16) * L_ATT + tc4);
    __syncthreads();
    short* op = xt + ((size_t)n * L_ATT + l0) * 512 + k0;
#pragma unroll
    for (int r = 0; r < 4; ++r) {
        int l = tr + r * 16;
        short4 o = { f2b(s[tc4 + 0][l]), f2b(s[tc4 + 1][l]),
                     f2b(s[tc4 + 2][l]), f2b(s[tc4 + 3][l]) };
        *(short4*)(op + (size_t)l * 512 + tc4) = o;
    }
}

// ---------------------------------------------------------------------------
// qkv 1x1 conv as MFMA GEMM (R6 4-wave shape), fragments straight from global.
// Flat grid 432, XCD-swizzled. Epilogue: q(xQSCALE_LOG2E)->qt8[l][8] short4,
// k->kt8[l][8] short4, v->vt[d][l] + vle[l][64] short4.
// ---------------------------------------------------------------------------
__global__ __launch_bounds__(256) void qkv_kernel(
    const short* __restrict__ xt, const short* __restrict__ wqb,
    const float* __restrict__ qkv_b, short* __restrict__ qt8,
    short* __restrict__ kt8, short* __restrict__ vt, short* __restrict__ vle)
{
    const int g = blockIdx.x;              // 432 = 8 * 54
    const int xcd = g & 7, rr = g >> 3;    // rr < 54
    const int y = rr % 3, grp = rr / 3;    // grp < 18
    const int code = grp * 8 + xcd;        // = ltile + 36*n, < 144
    const int l0 = (code % 36) * 64, oc0 = y * 64, n = code / 36;

    const int lane = threadIdx.x & 63, wave = threadIdx.x >> 6;
    const int col = lane & 15, quad = lane >> 4;
    const int ocb = oc0 + wave * 16;

    f4 acc[4];
#pragma unroll
    for (int nt = 0; nt < 4; ++nt) acc[nt] = (f4){0.f, 0.f, 0.f, 0.f};

    const short* arow = wqb + (size_t)(ocb + col) * 512 + quad * 8;
    const short* brow = xt + ((size_t)n * L_ATT + l0 + col) * 512 + quad * 8;

#pragma unroll 4
    for (int k0 = 0; k0 < 512; k0 += 32) {
        bh8 af = *(const bh8*)(arow + k0);
        bh8 b0 = *(const bh8*)(brow + k0);
        bh8 b1 = *(const bh8*)(brow + (size_t)16 * 512 + k0);
        bh8 b2 = *(const bh8*)(brow + (size_t)32 * 512 + k0);
        bh8 b3 = *(const bh8*)(brow + (size_t)48 * 512 + k0);
        acc[0] = __builtin_amdgcn_mfma_f32_16x16x32_bf16(af, b0, acc[0], 0, 0, 0);
        acc[1] = __builtin_amdgcn_mfma_f32_16x16x32_bf16(af, b1, acc[1], 0, 0, 0);
        acc[2] = __builtin_amdgcn_mfma_f32_16x16x32_bf16(af, b2, acc[2], 0, 0, 0);
        acc[3] = __builtin_amdgcn_mfma_f32_16x16x32_bf16(af, b3, acc[3], 0, 0, 0);
    }

    const int obase = ocb + quad * 4;       // multiple of 4; r0 never straddles
    const int h = obase / 24;
    const int r0 = obase - h * 24;
    const int slice = n * 8 + h;

#pragma unroll
    for (int nt = 0; nt < 4; ++nt) {
        int l = l0 + nt * 16 + col;
        float v[4];
#pragma unroll
        for (int reg = 0; reg < 4; ++reg) v[reg] = acc[nt][reg] + qkv_b[obase + reg];
        if (r0 < 8) {          // q: scale, pack short4
            short4 o = { f2b(v[0] * QSCALE_LOG2E), f2b(v[1] * QSCALE_LOG2E),
                         f2b(v[2] * QSCALE_LOG2E), f2b(v[3] * QSCALE_LOG2E) };
            *(short4*)(qt8 + ((size_t)slice * L_ATT + l) * 8 + r0) = o;
        } else if (r0 < 16) {  // k
            short4 o = { f2b(v[0]), f2b(v[1]), f2b(v[2]), f2b(v[3]) };
            *(short4*)(kt8 + ((size_t)slice * L_ATT + l) * 8 + (r0 - 8)) = o;
        } else {               // v
            short4 o = { f2b(v[0]), f2b(v[1]), f2b(v[2]), f2b(v[3]) };
            int d0 = r0 - 16;
#pragma unroll
            for (int reg = 0; reg < 4; ++reg)
                vt[((size_t)slice * 8 + d0 + reg) * L_ATT + l] = ((short*)&o)[reg];
            *(short4*)(vle + ((size_t)n * L_ATT + l) * 64 + h * 8 + d0) = o;
        }
    }
}

// ---------------------------------------------------------------------------
// Flash attention, zero LDS, fully BRANCHLESS hot loop: lanes whose fragment
// slots are structural zeros/ones point at a 32B constant page with per-lane
// stride 0; real lanes stride through kt8/vt. All loads unconditional ->
// compiler can software-pipeline. Register double-buffer retained.
// Flat grid 1152, XCD-swizzled (h = g&7). S^T = K.Q^T (permuted key map),
// exp2, pack via v_perm, PV: O^T = V.P^T with ones-row d=8 -> lsum free.
// ---------------------------------------------------------------------------
__global__ __launch_bounds__(256) void attn_kernel(
    const short* __restrict__ qt8, const short* __restrict__ kt8,
    const short* __restrict__ vt, const short* __restrict__ cpage,
    float* __restrict__ t32)
{
    const int g = blockIdx.x;              // 1152 = 8 * 144
    const int h = g & 7, r = g >> 3;       // r < 144
    const int n = r / 36;
    const int q0 = (r % 36) * 64;
    const int slice = n * 8 + h;
    const int lane = threadIdx.x & 63, wave = threadIdx.x >> 6;
    const int col = lane & 15, quad = lane >> 4;

    const short* qs = qt8 + (size_t)slice * L_ATT * 8;
    const short* ks8 = kt8 + (size_t)slice * L_ATT * 8;
    const short* vb = vt + (size_t)slice * 8 * L_ATT;
    const short* cones = cpage;
    const short* czero = cpage + 8;

    bh8 zero8 = {0, 0, 0, 0, 0, 0, 0, 0};
    bh8 qf = zero8;
    if (quad == 0)
        qf = *(const bh8*)(qs + (size_t)(q0 + wave * 16 + col) * 8);

    // per-lane pointers + strides (zeros/ones lanes: const page, stride 0)
    const int koff = 8 * (col >> 2) + (col & 3);
    const short* kp[4];
    const int kstep = (quad == 0) ? 64 * 8 : 0;
#pragma unroll
    for (int nt = 0; nt < 4; ++nt)
        kp[nt] = (quad == 0)
               ? ks8 + (size_t)(32 * (nt >> 1) + 4 * (nt & 1) + koff) * 8
               : czero;
    const short* vp[2];
    const int vstep = (col < 8) ? 64 : 0;
#pragma unroll
    for (int ks = 0; ks < 2; ++ks)
        vp[ks] = (col < 8) ? vb + (size_t)col * L_ATT + ks * 32 + quad * 8
                           : ((col == 8) ? cones : czero);

    // register double-buffer; preload tile 0
    bh8 kb[2][4], vbf[2][2];
#pragma unroll
    for (int nt = 0; nt < 4; ++nt) { kb[0][nt] = *(const bh8*)kp[nt]; kp[nt] += kstep; }
#pragma unroll
    for (int ks = 0; ks < 2; ++ks) { vbf[0][ks] = *(const bh8*)vp[ks]; vp[ks] += vstep; }

    f4 oacc = (f4){0.f, 0.f, 0.f, 0.f};

#pragma unroll 2
    for (int t = 0; t < 36; ++t) {
        const int p = t & 1, pn = p ^ 1;
        // unconditional prefetch (last iter overruns harmlessly inside ws)
#pragma unroll
        for (int nt = 0; nt < 4; ++nt) { kb[pn][nt] = *(const bh8*)kp[nt]; kp[nt] += kstep; }
#pragma unroll
        for (int ks = 0; ks < 2; ++ks) { vbf[pn][ks] = *(const bh8*)vp[ks]; vp[ks] += vstep; }

        f4 s[4];
#pragma unroll
        for (int nt = 0; nt < 4; ++nt) {
            f4 z = (f4){0.f, 0.f, 0.f, 0.f};
            s[nt] = __builtin_amdgcn_mfma_f32_16x16x32_bf16(kb[p][nt], qf, z, 0, 0, 0);
        }
        float e[4][4];
#pragma unroll
        for (int nt = 0; nt < 4; ++nt)
#pragma unroll
            for (int reg = 0; reg < 4; ++reg)
                e[nt][reg] = EXP2(s[nt][reg]);
#pragma unroll
        for (int ks = 0; ks < 2; ++ks) {
            union { int i[4]; bh8 v; } pu;
            pu.i[0] = packhi(e[2 * ks][0],     e[2 * ks][1]);
            pu.i[1] = packhi(e[2 * ks][2],     e[2 * ks][3]);
            pu.i[2] = packhi(e[2 * ks + 1][0], e[2 * ks + 1][1]);
            pu.i[3] = packhi(e[2 * ks + 1][2], e[2 * ks + 1][3]);
            oacc = __builtin_amdgcn_mfma_f32_16x16x32_bf16(vbf[p][ks], pu.v, oacc, 0, 0, 0);
        }
    }

    // O^T rows: quad0 -> d0..3, quad1 -> d4..7, quad2/reg0 -> lsum (row 8).
    float ls = __shfl(oacc[0], 32 + col, 64);
    float inv = 1.0f / ls;
    if (quad < 2) {
        int qg = q0 + wave * 16 + col;
        float4 o = { oacc[0] * inv, oacc[1] * inv, oacc[2] * inv, oacc[3] * inv };
        *(float4*)(t32 + ((size_t)n * L_ATT + qg) * 64 + h * 8 + quad * 4) = o;
    }
}

// ---------------------------------------------------------------------------
// 3x3 SAME pos-conv as MFMA implicit GEMM, t-SPLIT across 4 waves:
// block 256 = 4 waves, wave w owns oc-strip w*16; 18 mfma/wave.
// grid (144, 4) = 576 blocks -> 9 waves/CU (was 2.25). No LDS.
// ---------------------------------------------------------------------------
__global__ __launch_bounds__(256) void posconv_kernel(
    const short* __restrict__ vle, const short* __restrict__ wqp,
    const float* __restrict__ pbias, const float* __restrict__ t32,
    short* __restrict__ tbh)
{
    const int n = blockIdx.y;
    const int lane = threadIdx.x & 63;
    const int t = threadIdx.x >> 6;          // oc-strip = wave id
    const int l0 = blockIdx.x * 16;
    const int col = lane & 15, quad = lane >> 4;

    const int la = l0 + col;                 // A-row this lane feeds
    const int ya = la / 48, xa = la - ya * 48;

    f4 acc = (f4){0.f, 0.f, 0.f, 0.f};
    const short* vbase = vle + (size_t)n * L_ATT * 64;

#pragma unroll
    for (int q = 0; q < 9; ++q) {
        const int dy = q / 3 - 1, dx = q - (q / 3) * 3 - 1;
        const bool valid = ((unsigned)(ya + dy) < 48u) && ((unsigned)(xa + dx) < 48u);
        const short* ap = vbase + (size_t)(la + dy * 48 + dx) * 64 + quad * 8;
#pragma unroll
        for (int ks = 0; ks < 2; ++ks) {
            bh8 af = {0, 0, 0, 0, 0, 0, 0, 0};
            if (valid) af = *(const bh8*)(ap + ks * 32);
            bh8 bf = *(const bh8*)(wqp + ((size_t)q * 64 + t * 16 + col) * 64
                                   + ks * 32 + quad * 8);
            acc = __builtin_amdgcn_mfma_f32_16x16x32_bf16(af, bf, acc, 0, 0, 0);
        }
    }

    const float* tp = t32 + (size_t)n * L_ATT * 64;
    short* op = tbh + (size_t)n * L_ATT * 64;
    const int oc = t * 16 + col;
    const float bb = pbias[oc];
#pragma unroll
    for (int reg = 0; reg < 4; ++reg) {
        int l = l0 + quad * 4 + reg;
        size_t idx = (size_t)l * 64 + oc;
        op[idx] = f2b(acc[reg] + tp[idx] + bb);
    }
}

// ---------------------------------------------------------------------------
// res 1x1 conv: out[n][oc][l], K=64, fragments direct from global.
// Flat grid 1152, XCD-swizzled.
// ---------------------------------------------------------------------------
__global__ __launch_bounds__(256) void res_kernel(
    const short* __restrict__ tbh, const short* __restrict__ reswb,
    const float* __restrict__ res_b, float* __restrict__ out)
{
    const int g = blockIdx.x;              // 1152 = 8 * 144
    const int xcd = g & 7, rr = g >> 3;    // rr < 144
    const int y = rr & 7, grp = rr >> 3;   // grp < 18
    const int code = grp * 8 + xcd;        // < 144
    const int l0 = (code % 36) * 64, oc0 = y * 64, n = code / 36;

    const int lane = threadIdx.x & 63, wave = threadIdx.x >> 6;
    const int col = lane & 15, quad = lane >> 4;
    const int ocb = oc0 + wave * 16;

    f4 acc[4];
#pragma unroll
    for (int nt = 0; nt < 4; ++nt) acc[nt] = (f4){0.f, 0.f, 0.f, 0.f};

#pragma unroll
    for (int ks = 0; ks < 2; ++ks) {
        bh8 af = *(const bh8*)(reswb + (size_t)(ocb + col) * 64 + ks * 32 + quad * 8);
#pragma unroll
        for (int nt = 0; nt < 4; ++nt) {
            bh8 bf = *(const bh8*)(tbh + ((size_t)n * L_ATT + l0 + nt * 16 + col) * 64
                                   + ks * 32 + quad * 8);
            acc[nt] = __builtin_amdgcn_mfma_f32_16x16x32_bf16(af, bf, acc[nt], 0, 0, 0);
        }
    }

#pragma unroll
    for (int nt = 0; nt < 4; ++nt) {
        int l = l0 + nt * 16 + col;
#pragma unroll
        for (int reg = 0; reg < 4; ++reg) {
            int oc = ocb + quad * 4 + reg;
            out[((size_t)n * 512 + oc) * L_ATT + l] = acc[nt][reg] + res_b[oc];
        }
    }
}

// ---------------------------------------------------------------------------
extern "C" void kernel_launch(void* const* d_in, const int* in_sizes, int n_in,
                              void* d_out, int out_size, void* d_ws, size_t ws_size,
                              hipStream_t stream)
{
    const float* x      = (const float*)d_in[0];
    const float* qkv_w  = (const float*)d_in[1];
    const float* qkv_b  = (const float*)d_in[2];
    const float* pos_w  = (const float*)d_in[3];
    const float* pos_b  = (const float*)d_in[4];
    const float* res_w  = (const float*)d_in[5];
    const float* res_b  = (const float*)d_in[6];
    float* out = (float*)d_out;

    char* ws = (char*)d_ws;
    short* xt    = (short*)(ws);                    //  9,437,184 B: [4][2304][512]
    short* qt8   = (short*)(ws + 9437184);          //  1,179,648 B: [32][2304][8]
    short* kt8   = (short*)(ws + 10616832);         //  1,179,648 B: [32][2304][8]
    short* vt    = (short*)(ws + 11796480);         //  1,179,648 B: [32][8][2304]
    short* tbh   = (short*)(ws + 12976128);         //  1,179,648 B: [4][2304][64]
    short* wqb   = (short*)(ws + 14155776);         //    196,608 B: [192][512]
    short* reswb = (short*)(ws + 14352384);         //     65,536 B: [512][64]
    short* vle   = (short*)(ws + 14417920);         //  1,179,648 B: [4][2304][64]
    short* wqp   = (short*)(ws + 15597568);         //     73,728 B: [9][64][64]
    short* cpage = (short*)(ws + 15671296);         //         32 B: ones8 + zero8
    float* t32   = (float*)d_out;                   // scratch [4][2304][64] fp32

    wcvt_kernel<<<273, 256, 0, stream>>>(qkv_w, res_w, pos_w, wqb, reswb, wqp, cpage);
    xt_kernel<<<dim3(36, 8, 4), 256, 0, stream>>>(x, xt);
    qkv_kernel<<<432, 256, 0, stream>>>(xt, wqb, qkv_b, qt8, kt8, vt, vle);
    attn_kernel<<<1152, 256, 0, stream>>>(qt8, kt8, vt, cpage, t32);
    posconv_kernel<<<dim3(144, 4), 256, 0, stream>>>(vle, wqp, pos_b, t32, tbh);
    res_kernel<<<1152, 256, 0, stream>>>(tbh, reswb, res_b, out);
}

// Round 9
// 163.310 us; speedup vs baseline: 1.1100x; 1.0793x over previous
//
#include <hip/hip_runtime.h>

#define L_ATT 2304
// SCALE * log2(e): softmax via exp2 is mathematically identical
#define QSCALE_LOG2E 0.5100695712f

using bh8 = __attribute__((ext_vector_type(8))) short;  // 8 bf16 (4 VGPRs)
using f4  = __attribute__((ext_vector_type(4))) float;  // 4 fp32 acc

#if __has_builtin(__builtin_amdgcn_exp2f)
#define EXP2(x) __builtin_amdgcn_exp2f(x)
#else
#define EXP2(x) exp2f(x)
#endif

__device__ inline short f2b(float f) {   // RNE
    union { float f; unsigned u; } c; c.f = f;
    unsigned r = (c.u + 0x7FFFu + ((c.u >> 16) & 1u)) >> 16;
    return (short)r;
}
// pack hi16(lo), hi16(hi) -> one dword (two bf16, truncation; bias cancels in softmax)
__device__ inline int packhi(float lo, float hi) {
    return (int)__builtin_amdgcn_perm(__float_as_uint(hi), __float_as_uint(lo), 0x07060302u);
}

// ---------------------------------------------------------------------------
// Weight conversion. grid 272 x 256.
// qkv_w (192x512) + res_w (512x64) fp32->bf16; pos_w -> wqp[q][oc][ic].
// ---------------------------------------------------------------------------
__global__ __launch_bounds__(256) void wcvt_kernel(
    const float* __restrict__ qkv_w, const float* __restrict__ res_w,
    const float* __restrict__ pos_w,
    short* __restrict__ wqb, short* __restrict__ reswb, short* __restrict__ wqp)
{
    int j = blockIdx.x * 256 + threadIdx.x;
    if (j < 24576) {
        float4 v = ((const float4*)qkv_w)[j];
        short4 o = { f2b(v.x), f2b(v.y), f2b(v.z), f2b(v.w) };
        *(short4*)(wqb + (size_t)j * 4) = o;
    } else if (j < 32768) {
        int idx = j - 24576;
        float4 v = ((const float4*)res_w)[idx];
        short4 o = { f2b(v.x), f2b(v.y), f2b(v.z), f2b(v.w) };
        *(short4*)(reswb + (size_t)idx * 4) = o;
    } else if (j < 69632) {
        int e = j - 32768;                 // e = q*4096 + (oc*64+ic)
        wqp[e] = f2b(pos_w[(size_t)(e & 4095) * 9 + (e >> 12)]);
    }
}

// ---------------------------------------------------------------------------
// x [n][512][2304] fp32 -> xt [n][2304][512] bf16 (LDS tile transpose).
// grid (36, 8, 4)
// ---------------------------------------------------------------------------
__global__ __launch_bounds__(256) void xt_kernel(
    const float* __restrict__ x, short* __restrict__ xt)
{
    const int l0 = blockIdx.x * 64, k0 = blockIdx.y * 64, n = blockIdx.z;
    __shared__ float s[64][68];
    const int tr = threadIdx.x >> 4, tc4 = (threadIdx.x & 15) * 4;
    const float* xp = x + ((size_t)n * 512 + k0) * L_ATT + l0;
#pragma unroll
    for (int r = 0; r < 4; ++r)
        *(float4*)&s[tr + r * 16][tc4] =
            *(const float4*)(xp + (size_t)(tr + r * 16) * L_ATT + tc4);
    __syncthreads();
    short* op = xt + ((size_t)n * L_ATT + l0) * 512 + k0;
#pragma unroll
    for (int r = 0; r < 4; ++r) {
        int l = tr + r * 16;
        short4 o = { f2b(s[tc4 + 0][l]), f2b(s[tc4 + 1][l]),
                     f2b(s[tc4 + 2][l]), f2b(s[tc4 + 3][l]) };
        *(short4*)(op + (size_t)l * 512 + tc4) = o;
    }
}

// ---------------------------------------------------------------------------
// qkv 1x1 conv as MFMA GEMM (4-wave shape), fragments straight from global.
// Flat grid 432, XCD-swizzled. Epilogue: q(xQSCALE_LOG2E)->qt8[l][8] short4,
// k->kt8[l][8] short4, v->vt[d][l] + vle[l][64] short4.
// ---------------------------------------------------------------------------
__global__ __launch_bounds__(256) void qkv_kernel(
    const short* __restrict__ xt, const short* __restrict__ wqb,
    const float* __restrict__ qkv_b, short* __restrict__ qt8,
    short* __restrict__ kt8, short* __restrict__ vt, short* __restrict__ vle)
{
    const int g = blockIdx.x;              // 432 = 8 * 54
    const int xcd = g & 7, rr = g >> 3;    // rr < 54
    const int y = rr % 3, grp = rr / 3;    // grp < 18
    const int code = grp * 8 + xcd;        // = ltile + 36*n, < 144
    const int l0 = (code % 36) * 64, oc0 = y * 64, n = code / 36;

    const int lane = threadIdx.x & 63, wave = threadIdx.x >> 6;
    const int col = lane & 15, quad = lane >> 4;
    const int ocb = oc0 + wave * 16;

    f4 acc[4];
#pragma unroll
    for (int nt = 0; nt < 4; ++nt) acc[nt] = (f4){0.f, 0.f, 0.f, 0.f};

    const short* arow = wqb + (size_t)(ocb + col) * 512 + quad * 8;
    const short* brow = xt + ((size_t)n * L_ATT + l0 + col) * 512 + quad * 8;

#pragma unroll 4
    for (int k0 = 0; k0 < 512; k0 += 32) {
        bh8 af = *(const bh8*)(arow + k0);
        bh8 b0 = *(const bh8*)(brow + k0);
        bh8 b1 = *(const bh8*)(brow + (size_t)16 * 512 + k0);
        bh8 b2 = *(const bh8*)(brow + (size_t)32 * 512 + k0);
        bh8 b3 = *(const bh8*)(brow + (size_t)48 * 512 + k0);
        acc[0] = __builtin_amdgcn_mfma_f32_16x16x32_bf16(af, b0, acc[0], 0, 0, 0);
        acc[1] = __builtin_amdgcn_mfma_f32_16x16x32_bf16(af, b1, acc[1], 0, 0, 0);
        acc[2] = __builtin_amdgcn_mfma_f32_16x16x32_bf16(af, b2, acc[2], 0, 0, 0);
        acc[3] = __builtin_amdgcn_mfma_f32_16x16x32_bf16(af, b3, acc[3], 0, 0, 0);
    }

    const int obase = ocb + quad * 4;       // multiple of 4; r0 never straddles
    const int h = obase / 24;
    const int r0 = obase - h * 24;
    const int slice = n * 8 + h;

#pragma unroll
    for (int nt = 0; nt < 4; ++nt) {
        int l = l0 + nt * 16 + col;
        float v[4];
#pragma unroll
        for (int reg = 0; reg < 4; ++reg) v[reg] = acc[nt][reg] + qkv_b[obase + reg];
        if (r0 < 8) {          // q: scale, pack short4
            short4 o = { f2b(v[0] * QSCALE_LOG2E), f2b(v[1] * QSCALE_LOG2E),
                         f2b(v[2] * QSCALE_LOG2E), f2b(v[3] * QSCALE_LOG2E) };
            *(short4*)(qt8 + ((size_t)slice * L_ATT + l) * 8 + r0) = o;
        } else if (r0 < 16) {  // k
            short4 o = { f2b(v[0]), f2b(v[1]), f2b(v[2]), f2b(v[3]) };
            *(short4*)(kt8 + ((size_t)slice * L_ATT + l) * 8 + (r0 - 8)) = o;
        } else {               // v
            short4 o = { f2b(v[0]), f2b(v[1]), f2b(v[2]), f2b(v[3]) };
            int d0 = r0 - 16;
#pragma unroll
            for (int reg = 0; reg < 4; ++reg)
                vt[((size_t)slice * 8 + d0 + reg) * L_ATT + l] = ((short*)&o)[reg];
            *(short4*)(vle + ((size_t)n * L_ATT + l) * 64 + h * 8 + d0) = o;
        }
    }
}

// ---------------------------------------------------------------------------
// Flash attention: LDS-shared K/V tiles (4 waves reuse one staged copy),
// 32 queries/wave (2 Q-frags), one barrier per 64-key tile, double-buffered.
// Staging: wave0 -> K tile PERMUTED so reader slot = nt*16+col (2-way banks);
// wave1 -> V tile with d-rotated rows (breaks 8-way conflict). ds_write is
// sunk below the tile's compute, so global->LDS latency is covered.
// Masked lanes read 32B const rows in LDS (broadcast). XOR toggles buffers.
// S^T = K.Q^T (permuted key map), exp2, pack via v_perm, PV: O^T = V.P^T,
// ones-row d=8 -> lsum free. grid 576 (= 8 * 72, h = g&7), block 256.
// ---------------------------------------------------------------------------
__global__ __launch_bounds__(256) void attn_kernel(
    const short* __restrict__ qt8, const short* __restrict__ kt8,
    const short* __restrict__ vt, float* __restrict__ t32)
{
    const int g = blockIdx.x;              // 576 = 8 * 72
    const int h = g & 7, r = g >> 3;       // r < 72
    const int n = r / 18;
    const int q0 = (r % 18) * 128;
    const int slice = n * 8 + h;
    const int tid = threadIdx.x;
    const int lane = tid & 63, wave = tid >> 6;
    const int col = lane & 15, quad = lane >> 4;

    // LDS shorts: K buf0 [0,512) K buf1 [512,1024) V buf0 [1024,1536)
    //             V buf1 [1536,2048) const [2048,2064): 8 ones, 8 zeros
    __shared__ short smem[2064];

    const short* qs  = qt8 + (size_t)slice * L_ATT * 8;
    const short* ks8 = kt8 + (size_t)slice * L_ATT * 8;
    const short* vb  = vt  + (size_t)slice * 8 * L_ATT;

    if (tid < 16) smem[2048 + tid] = (tid < 8) ? (short)0x3F80 : (short)0;

    bh8 zero8 = {0, 0, 0, 0, 0, 0, 0, 0};
    bh8 qf[2];
#pragma unroll
    for (int f = 0; f < 2; ++f) {
        qf[f] = zero8;
        if (quad == 0)
            qf[f] = *(const bh8*)(qs + (size_t)(q0 + wave * 32 + f * 16 + col) * 8);
    }

    // reader offsets (shorts); XOR toggles double buffer for active lanes only
    const int kxor = (quad == 0) ? 512 : 0;
    int kidx[4];
#pragma unroll
    for (int nt = 0; nt < 4; ++nt)
        kidx[nt] = (quad == 0) ? (nt * 16 + col) * 8 : 2056;     // 2056 = zeros
    const int vxor = (col < 8) ? 512 : 0;
    int vidx[2];
#pragma unroll
    for (int ks = 0; ks < 2; ++ks)
        vidx[ks] = (col < 8)
                 ? 1024 + col * 64 + ((ks * 32 + quad * 8 + col * 8) & 63)
                 : ((col == 8) ? 2048 : 2056);                   // 2048 = ones

    // staging slots
    const int ksl = ((lane >> 5) & 1) * 32 + ((lane >> 2) & 1) * 16
                  + ((lane >> 3) & 3) * 4 + (lane & 3);          // key permute
    const int vd = lane >> 3, vkc = (lane & 7) * 8;
    const int vsl = 1024 + vd * 64 + ((vkc + vd * 8) & 63);      // d-rotation

    // stage tile 0 into buf 0
    if (wave == 0)
        *(uint4*)&smem[ksl * 8] = *(const uint4*)(ks8 + (size_t)lane * 8);
    else if (wave == 1)
        *(uint4*)&smem[vsl] = *(const uint4*)(vb + (size_t)vd * L_ATT + vkc);
    __syncthreads();

    f4 oacc[2];
    oacc[0] = (f4){0.f, 0.f, 0.f, 0.f};
    oacc[1] = (f4){0.f, 0.f, 0.f, 0.f};

    int sofs = 512;   // staging buffer base toggle (shorts)
    for (int t = 0; t < 36; ++t) {
        // issue next tile's global loads NOW (t=35 overrun stays inside ws)
        uint4 dk, dv;
        if (wave == 0)
            dk = *(const uint4*)(ks8 + (size_t)((t + 1) * 64 + lane) * 8);
        else if (wave == 1)
            dv = *(const uint4*)(vb + (size_t)vd * L_ATT + (t + 1) * 64 + vkc);

        bh8 kf[4], vf[2];
#pragma unroll
        for (int nt = 0; nt < 4; ++nt) kf[nt] = *(const bh8*)&smem[kidx[nt]];
#pragma unroll
        for (int ks = 0; ks < 2; ++ks) vf[ks] = *(const bh8*)&smem[vidx[ks]];

#pragma unroll
        for (int f = 0; f < 2; ++f) {
            f4 s[4];
#pragma unroll
            for (int nt = 0; nt < 4; ++nt) {
                f4 z = (f4){0.f, 0.f, 0.f, 0.f};
                s[nt] = __builtin_amdgcn_mfma_f32_16x16x32_bf16(kf[nt], qf[f], z, 0, 0, 0);
            }
            float e[4][4];
#pragma unroll
            for (int nt = 0; nt < 4; ++nt)
#pragma unroll
                for (int reg = 0; reg < 4; ++reg)
                    e[nt][reg] = EXP2(s[nt][reg]);
#pragma unroll
            for (int ks = 0; ks < 2; ++ks) {
                union { int i[4]; bh8 v; } pu;
                pu.i[0] = packhi(e[2 * ks][0],     e[2 * ks][1]);
                pu.i[1] = packhi(e[2 * ks][2],     e[2 * ks][3]);
                pu.i[2] = packhi(e[2 * ks + 1][0], e[2 * ks + 1][1]);
                pu.i[3] = packhi(e[2 * ks + 1][2], e[2 * ks + 1][3]);
                oacc[f] = __builtin_amdgcn_mfma_f32_16x16x32_bf16(vf[ks], pu.v, oacc[f], 0, 0, 0);
            }
        }

        // sink the staging stores below compute (load->use distance = 1 tile)
        if (wave == 0)      *(uint4*)&smem[sofs + ksl * 8] = dk;
        else if (wave == 1) *(uint4*)&smem[sofs + vsl] = dv;

#pragma unroll
        for (int nt = 0; nt < 4; ++nt) kidx[nt] ^= kxor;
        vidx[0] ^= vxor; vidx[1] ^= vxor;
        sofs ^= 512;
        __syncthreads();
    }

    // O^T rows: quad0 -> d0..3, quad1 -> d4..7, quad2/reg0 -> lsum (row 8).
#pragma unroll
    for (int f = 0; f < 2; ++f) {
        float ls = __shfl(oacc[f][0], 32 + col, 64);
        float inv = 1.0f / ls;
        if (quad < 2) {
            int qg = q0 + wave * 32 + f * 16 + col;
            float4 o = { oacc[f][0] * inv, oacc[f][1] * inv,
                         oacc[f][2] * inv, oacc[f][3] * inv };
            *(float4*)(t32 + ((size_t)n * L_ATT + qg) * 64 + h * 8 + quad * 4) = o;
        }
    }
}

// ---------------------------------------------------------------------------
// 3x3 SAME pos-conv as MFMA implicit GEMM, t-SPLIT across 4 waves:
// block 256 = 4 waves, wave w owns oc-strip w*16; 18 mfma/wave.
// grid (144, 4) = 576 blocks. No LDS.
// ---------------------------------------------------------------------------
__global__ __launch_bounds__(256) void posconv_kernel(
    const short* __restrict__ vle, const short* __restrict__ wqp,
    const float* __restrict__ pbias, const float* __restrict__ t32,
    short* __restrict__ tbh)
{
    const int n = blockIdx.y;
    const int lane = threadIdx.x & 63;
    const int t = threadIdx.x >> 6;          // oc-strip = wave id
    const int l0 = blockIdx.x * 16;
    const int col = lane & 15, quad = lane >> 4;

    const int la = l0 + col;                 // A-row this lane feeds
    const int ya = la / 48, xa = la - ya * 48;

    f4 acc = (f4){0.f, 0.f, 0.f, 0.f};
    const short* vbase = vle + (size_t)n * L_ATT * 64;

#pragma unroll
    for (int q = 0; q < 9; ++q) {
        const int dy = q / 3 - 1, dx = q - (q / 3) * 3 - 1;
        const bool valid = ((unsigned)(ya + dy) < 48u) && ((unsigned)(xa + dx) < 48u);
        const short* ap = vbase + (size_t)(la + dy * 48 + dx) * 64 + quad * 8;
#pragma unroll
        for (int ks = 0; ks < 2; ++ks) {
            bh8 af = {0, 0, 0, 0, 0, 0, 0, 0};
            if (valid) af = *(const bh8*)(ap + ks * 32);
            bh8 bf = *(const bh8*)(wqp + ((size_t)q * 64 + t * 16 + col) * 64
                                   + ks * 32 + quad * 8);
            acc = __builtin_amdgcn_mfma_f32_16x16x32_bf16(af, bf, acc, 0, 0, 0);
        }
    }

    const float* tp = t32 + (size_t)n * L_ATT * 64;
    short* op = tbh + (size_t)n * L_ATT * 64;
    const int oc = t * 16 + col;
    const float bb = pbias[oc];
#pragma unroll
    for (int reg = 0; reg < 4; ++reg) {
        int l = l0 + quad * 4 + reg;
        size_t idx = (size_t)l * 64 + oc;
        op[idx] = f2b(acc[reg] + tp[idx] + bb);
    }
}

// ---------------------------------------------------------------------------
// res 1x1 conv: out[n][oc][l], K=64, fragments direct from global.
// Flat grid 1152, XCD-swizzled.
// ---------------------------------------------------------------------------
__global__ __launch_bounds__(256) void res_kernel(
    const short* __restrict__ tbh, const short* __restrict__ reswb,
    const float* __restrict__ res_b, float* __restrict__ out)
{
    const int g = blockIdx.x;              // 1152 = 8 * 144
    const int xcd = g & 7, rr = g >> 3;    // rr < 144
    const int y = rr & 7, grp = rr >> 3;   // grp < 18
    const int code = grp * 8 + xcd;        // < 144
    const int l0 = (code % 36) * 64, oc0 = y * 64, n = code / 36;

    const int lane = threadIdx.x & 63, wave = threadIdx.x >> 6;
    const int col = lane & 15, quad = lane >> 4;
    const int ocb = oc0 + wave * 16;

    f4 acc[4];
#pragma unroll
    for (int nt = 0; nt < 4; ++nt) acc[nt] = (f4){0.f, 0.f, 0.f, 0.f};

#pragma unroll
    for (int ks = 0; ks < 2; ++ks) {
        bh8 af = *(const bh8*)(reswb + (size_t)(ocb + col) * 64 + ks * 32 + quad * 8);
#pragma unroll
        for (int nt = 0; nt < 4; ++nt) {
            bh8 bf = *(const bh8*)(tbh + ((size_t)n * L_ATT + l0 + nt * 16 + col) * 64
                                   + ks * 32 + quad * 8);
            acc[nt] = __builtin_amdgcn_mfma_f32_16x16x32_bf16(af, bf, acc[nt], 0, 0, 0);
        }
    }

#pragma unroll
    for (int nt = 0; nt < 4; ++nt) {
        int l = l0 + nt * 16 + col;
#pragma unroll
        for (int reg = 0; reg < 4; ++reg) {
            int oc = ocb + quad * 4 + reg;
            out[((size_t)n * 512 + oc) * L_ATT + l] = acc[nt][reg] + res_b[oc];
        }
    }
}

// ---------------------------------------------------------------------------
extern "C" void kernel_launch(void* const* d_in, const int* in_sizes, int n_in,
                              void* d_out, int out_size, void* d_ws, size_t ws_size,
                              hipStream_t stream)
{
    const float* x      = (const float*)d_in[0];
    const float* qkv_w  = (const float*)d_in[1];
    const float* qkv_b  = (const float*)d_in[2];
    const float* pos_w  = (const float*)d_in[3];
    const float* pos_b  = (const float*)d_in[4];
    const float* res_w  = (const float*)d_in[5];
    const float* res_b  = (const float*)d_in[6];
    float* out = (float*)d_out;

    char* ws = (char*)d_ws;
    short* xt    = (short*)(ws);                    //  9,437,184 B: [4][2304][512]
    short* qt8   = (short*)(ws + 9437184);          //  1,179,648 B: [32][2304][8]
    short* kt8   = (short*)(ws + 10616832);         //  1,179,648 B: [32][2304][8]
    short* vt    = (short*)(ws + 11796480);         //  1,179,648 B: [32][8][2304]
    short* tbh   = (short*)(ws + 12976128);         //  1,179,648 B: [4][2304][64]
    short* wqb   = (short*)(ws + 14155776);         //    196,608 B: [192][512]
    short* reswb = (short*)(ws + 14352384);         //     65,536 B: [512][64]
    short* vle   = (short*)(ws + 14417920);         //  1,179,648 B: [4][2304][64]
    short* wqp   = (short*)(ws + 15597568);         //     73,728 B: [9][64][64]
    float* t32   = (float*)d_out;                   // scratch [4][2304][64] fp32

    wcvt_kernel<<<272, 256, 0, stream>>>(qkv_w, res_w, pos_w, wqb, reswb, wqp);
    xt_kernel<<<dim3(36, 8, 4), 256, 0, stream>>>(x, xt);
    qkv_kernel<<<432, 256, 0, stream>>>(xt, wqb, qkv_b, qt8, kt8, vt, vle);
    attn_kernel<<<576, 256, 0, stream>>>(qt8, kt8, vt, t32);
    posconv_kernel<<<dim3(144, 4), 256, 0, stream>>>(vle, wqp, pos_b, t32, tbh);
    res_kernel<<<1152, 256, 0, stream>>>(tbh, reswb, res_b, out);
}

// Round 10
// 158.485 us; speedup vs baseline: 1.1438x; 1.0304x over previous
//
#include <hip/hip_runtime.h>

#define L_ATT 2304
// SCALE * log2(e): softmax via exp2 is mathematically identical
#define QSCALE_LOG2E 0.5100695712f

using bh8 = __attribute__((ext_vector_type(8))) short;  // 8 bf16 (4 VGPRs)
using f4  = __attribute__((ext_vector_type(4))) float;  // 4 fp32 acc

#if __has_builtin(__builtin_amdgcn_exp2f)
#define EXP2(x) __builtin_amdgcn_exp2f(x)
#else
#define EXP2(x) exp2f(x)
#endif

__device__ inline short f2b(float f) {   // RNE
    union { float f; unsigned u; } c; c.f = f;
    unsigned r = (c.u + 0x7FFFu + ((c.u >> 16) & 1u)) >> 16;
    return (short)r;
}
__device__ inline float b2f(short s) {
    union { unsigned u; float f; } c;
    c.u = ((unsigned)(unsigned short)s) << 16;
    return c.f;
}
// pack hi16(lo), hi16(hi) -> one dword (two bf16, truncation)
__device__ inline int packhi(float lo, float hi) {
    return (int)__builtin_amdgcn_perm(__float_as_uint(hi), __float_as_uint(lo), 0x07060302u);
}

// ---------------------------------------------------------------------------
// prep = wcvt (g<272) U xt transpose (g>=272). 1424 blocks x 256.
// wcvt: qkv_w/res_w fp32->bf16; pos_w -> wqp[q][oc][ic].
// xt: x [n][512][2304] fp32 -> xt [n][2304][512] bf16 via LDS tile.
// ---------------------------------------------------------------------------
__global__ __launch_bounds__(256) void prep_kernel(
    const float* __restrict__ x, const float* __restrict__ qkv_w,
    const float* __restrict__ res_w, const float* __restrict__ pos_w,
    short* __restrict__ xt, short* __restrict__ wqb,
    short* __restrict__ reswb, short* __restrict__ wqp)
{
    __shared__ float s[64][68];
    const int g = blockIdx.x;
    if (g < 272) {
        int j = g * 256 + threadIdx.x;
        if (j < 24576) {
            float4 v = ((const float4*)qkv_w)[j];
            short4 o = { f2b(v.x), f2b(v.y), f2b(v.z), f2b(v.w) };
            *(short4*)(wqb + (size_t)j * 4) = o;
        } else if (j < 32768) {
            int idx = j - 24576;
            float4 v = ((const float4*)res_w)[idx];
            short4 o = { f2b(v.x), f2b(v.y), f2b(v.z), f2b(v.w) };
            *(short4*)(reswb + (size_t)idx * 4) = o;
        } else {
            int e = j - 32768;                 // e = q*4096 + (oc*64+ic)
            wqp[e] = f2b(pos_w[(size_t)(e & 4095) * 9 + (e >> 12)]);
        }
        return;
    }
    const int gg = g - 272;                    // 1152 = 36 * 8 * 4
    const int l0 = (gg % 36) * 64, k0 = ((gg / 36) & 7) * 64, n = gg / 288;
    const int tr = threadIdx.x >> 4, tc4 = (threadIdx.x & 15) * 4;
    const float* xp = x + ((size_t)n * 512 + k0) * L_ATT + l0;
#pragma unroll
    for (int r = 0; r < 4; ++r)
        *(float4*)&s[tr + r * 16][tc4] =
            *(const float4*)(xp + (size_t)(tr + r * 16) * L_ATT + tc4);
    __syncthreads();
    short* op = xt + ((size_t)n * L_ATT + l0) * 512 + k0;
#pragma unroll
    for (int r = 0; r < 4; ++r) {
        int l = tr + r * 16;
        short4 o = { f2b(s[tc4 + 0][l]), f2b(s[tc4 + 1][l]),
                     f2b(s[tc4 + 2][l]), f2b(s[tc4 + 3][l]) };
        *(short4*)(op + (size_t)l * 512 + tc4) = o;
    }
}

// ---------------------------------------------------------------------------
// qkv 1x1 conv as MFMA GEMM (4-wave shape), fragments straight from global.
// Flat grid 432, XCD-swizzled. Epilogue: q(xQSCALE_LOG2E)->qt8[l][8] short4,
// k->kt8[l][8] short4, v->vt[d][l] + vle[l][64] short4.
// ---------------------------------------------------------------------------
__global__ __launch_bounds__(256) void qkv_kernel(
    const short* __restrict__ xt, const short* __restrict__ wqb,
    const float* __restrict__ qkv_b, short* __restrict__ qt8,
    short* __restrict__ kt8, short* __restrict__ vt, short* __restrict__ vle)
{
    const int g = blockIdx.x;              // 432 = 8 * 54
    const int xcd = g & 7, rr = g >> 3;    // rr < 54
    const int y = rr % 3, grp = rr / 3;    // grp < 18
    const int code = grp * 8 + xcd;        // = ltile + 36*n, < 144
    const int l0 = (code % 36) * 64, oc0 = y * 64, n = code / 36;

    const int lane = threadIdx.x & 63, wave = threadIdx.x >> 6;
    const int col = lane & 15, quad = lane >> 4;
    const int ocb = oc0 + wave * 16;

    f4 acc[4];
#pragma unroll
    for (int nt = 0; nt < 4; ++nt) acc[nt] = (f4){0.f, 0.f, 0.f, 0.f};

    const short* arow = wqb + (size_t)(ocb + col) * 512 + quad * 8;
    const short* brow = xt + ((size_t)n * L_ATT + l0 + col) * 512 + quad * 8;

#pragma unroll 4
    for (int k0 = 0; k0 < 512; k0 += 32) {
        bh8 af = *(const bh8*)(arow + k0);
        bh8 b0 = *(const bh8*)(brow + k0);
        bh8 b1 = *(const bh8*)(brow + (size_t)16 * 512 + k0);
        bh8 b2 = *(const bh8*)(brow + (size_t)32 * 512 + k0);
        bh8 b3 = *(const bh8*)(brow + (size_t)48 * 512 + k0);
        acc[0] = __builtin_amdgcn_mfma_f32_16x16x32_bf16(af, b0, acc[0], 0, 0, 0);
        acc[1] = __builtin_amdgcn_mfma_f32_16x16x32_bf16(af, b1, acc[1], 0, 0, 0);
        acc[2] = __builtin_amdgcn_mfma_f32_16x16x32_bf16(af, b2, acc[2], 0, 0, 0);
        acc[3] = __builtin_amdgcn_mfma_f32_16x16x32_bf16(af, b3, acc[3], 0, 0, 0);
    }

    const int obase = ocb + quad * 4;       // multiple of 4; r0 never straddles
    const int h = obase / 24;
    const int r0 = obase - h * 24;
    const int slice = n * 8 + h;

#pragma unroll
    for (int nt = 0; nt < 4; ++nt) {
        int l = l0 + nt * 16 + col;
        float v[4];
#pragma unroll
        for (int reg = 0; reg < 4; ++reg) v[reg] = acc[nt][reg] + qkv_b[obase + reg];
        if (r0 < 8) {          // q: scale, pack short4
            short4 o = { f2b(v[0] * QSCALE_LOG2E), f2b(v[1] * QSCALE_LOG2E),
                         f2b(v[2] * QSCALE_LOG2E), f2b(v[3] * QSCALE_LOG2E) };
            *(short4*)(qt8 + ((size_t)slice * L_ATT + l) * 8 + r0) = o;
        } else if (r0 < 16) {  // k
            short4 o = { f2b(v[0]), f2b(v[1]), f2b(v[2]), f2b(v[3]) };
            *(short4*)(kt8 + ((size_t)slice * L_ATT + l) * 8 + (r0 - 8)) = o;
        } else {               // v
            short4 o = { f2b(v[0]), f2b(v[1]), f2b(v[2]), f2b(v[3]) };
            int d0 = r0 - 16;
#pragma unroll
            for (int reg = 0; reg < 4; ++reg)
                vt[((size_t)slice * 8 + d0 + reg) * L_ATT + l] = ((short*)&o)[reg];
            *(short4*)(vle + ((size_t)n * L_ATT + l) * 64 + h * 8 + d0) = o;
        }
    }
}

// ---------------------------------------------------------------------------
// attnpos = flash attention (g<576) U 3x3 pos-conv (g>=576) — independent
// halves, both depend only on qkv; fully concurrent (1152 blocks = 4.5/CU).
// attn: LDS-shared K/V tiles, 32 q/wave, double-buffered, writes t32 (ws).
// posconv: MFMA implicit GEMM, writes pcv = conv + pos_b (bf16, NO t32 read).
// ---------------------------------------------------------------------------
__global__ __launch_bounds__(256) void attnpos_kernel(
    const short* __restrict__ qt8, const short* __restrict__ kt8,
    const short* __restrict__ vt, const short* __restrict__ vle,
    const short* __restrict__ wqp, const float* __restrict__ pbias,
    float* __restrict__ t32, short* __restrict__ pcv)
{
    __shared__ short smem[2064];
    const int g = blockIdx.x;
    const int tid = threadIdx.x;
    const int lane = tid & 63, wave = tid >> 6;
    const int col = lane & 15, quad = lane >> 4;

    if (g < 576) {                         // ---- attention half ----
        const int h = g & 7, r = g >> 3;   // r < 72
        const int n = r / 18;
        const int q0 = (r % 18) * 128;
        const int slice = n * 8 + h;

        const short* qs  = qt8 + (size_t)slice * L_ATT * 8;
        const short* ks8 = kt8 + (size_t)slice * L_ATT * 8;
        const short* vb  = vt  + (size_t)slice * 8 * L_ATT;

        if (tid < 16) smem[2048 + tid] = (tid < 8) ? (short)0x3F80 : (short)0;

        bh8 zero8 = {0, 0, 0, 0, 0, 0, 0, 0};
        bh8 qf[2];
#pragma unroll
        for (int f = 0; f < 2; ++f) {
            qf[f] = zero8;
            if (quad == 0)
                qf[f] = *(const bh8*)(qs + (size_t)(q0 + wave * 32 + f * 16 + col) * 8);
        }

        const int kxor = (quad == 0) ? 512 : 0;
        int kidx[4];
#pragma unroll
        for (int nt = 0; nt < 4; ++nt)
            kidx[nt] = (quad == 0) ? (nt * 16 + col) * 8 : 2056;
        const int vxor = (col < 8) ? 512 : 0;
        int vidx[2];
#pragma unroll
        for (int ks = 0; ks < 2; ++ks)
            vidx[ks] = (col < 8)
                     ? 1024 + col * 64 + ((ks * 32 + quad * 8 + col * 8) & 63)
                     : ((col == 8) ? 2048 : 2056);

        const int ksl = ((lane >> 5) & 1) * 32 + ((lane >> 2) & 1) * 16
                      + ((lane >> 3) & 3) * 4 + (lane & 3);
        const int vd = lane >> 3, vkc = (lane & 7) * 8;
        const int vsl = 1024 + vd * 64 + ((vkc + vd * 8) & 63);

        if (wave == 0)
            *(uint4*)&smem[ksl * 8] = *(const uint4*)(ks8 + (size_t)lane * 8);
        else if (wave == 1)
            *(uint4*)&smem[vsl] = *(const uint4*)(vb + (size_t)vd * L_ATT + vkc);
        __syncthreads();

        f4 oacc[2];
        oacc[0] = (f4){0.f, 0.f, 0.f, 0.f};
        oacc[1] = (f4){0.f, 0.f, 0.f, 0.f};

        int sofs = 512;
        for (int t = 0; t < 36; ++t) {
            uint4 dk, dv;
            if (wave == 0)
                dk = *(const uint4*)(ks8 + (size_t)((t + 1) * 64 + lane) * 8);
            else if (wave == 1)
                dv = *(const uint4*)(vb + (size_t)vd * L_ATT + (t + 1) * 64 + vkc);

            bh8 kf[4], vf[2];
#pragma unroll
            for (int nt = 0; nt < 4; ++nt) kf[nt] = *(const bh8*)&smem[kidx[nt]];
#pragma unroll
            for (int ks = 0; ks < 2; ++ks) vf[ks] = *(const bh8*)&smem[vidx[ks]];

#pragma unroll
            for (int f = 0; f < 2; ++f) {
                f4 s[4];
#pragma unroll
                for (int nt = 0; nt < 4; ++nt) {
                    f4 z = (f4){0.f, 0.f, 0.f, 0.f};
                    s[nt] = __builtin_amdgcn_mfma_f32_16x16x32_bf16(kf[nt], qf[f], z, 0, 0, 0);
                }
                float e[4][4];
#pragma unroll
                for (int nt = 0; nt < 4; ++nt)
#pragma unroll
                    for (int reg = 0; reg < 4; ++reg)
                        e[nt][reg] = EXP2(s[nt][reg]);
#pragma unroll
                for (int ks = 0; ks < 2; ++ks) {
                    union { int i[4]; bh8 v; } pu;
                    pu.i[0] = packhi(e[2 * ks][0],     e[2 * ks][1]);
                    pu.i[1] = packhi(e[2 * ks][2],     e[2 * ks][3]);
                    pu.i[2] = packhi(e[2 * ks + 1][0], e[2 * ks + 1][1]);
                    pu.i[3] = packhi(e[2 * ks + 1][2], e[2 * ks + 1][3]);
                    oacc[f] = __builtin_amdgcn_mfma_f32_16x16x32_bf16(vf[ks], pu.v, oacc[f], 0, 0, 0);
                }
            }

            if (wave == 0)      *(uint4*)&smem[sofs + ksl * 8] = dk;
            else if (wave == 1) *(uint4*)&smem[sofs + vsl] = dv;

#pragma unroll
            for (int nt = 0; nt < 4; ++nt) kidx[nt] ^= kxor;
            vidx[0] ^= vxor; vidx[1] ^= vxor;
            sofs ^= 512;
            __syncthreads();
        }

#pragma unroll
        for (int f = 0; f < 2; ++f) {
            float ls = __shfl(oacc[f][0], 32 + col, 64);
            float inv = 1.0f / ls;
            if (quad < 2) {
                int qg = q0 + wave * 32 + f * 16 + col;
                float4 o = { oacc[f][0] * inv, oacc[f][1] * inv,
                             oacc[f][2] * inv, oacc[f][3] * inv };
                *(float4*)(t32 + ((size_t)n * L_ATT + qg) * 64 + h * 8 + quad * 4) = o;
            }
        }
        return;
    }

    // ---- posconv half ----
    const int gf = g - 576;                // 576 = 144 * 4
    const int l0 = (gf % 144) * 16, n = gf / 144;
    const int t = wave;                    // oc-strip = wave id

    const int la = l0 + col;
    const int ya = la / 48, xa = la - ya * 48;

    f4 acc = (f4){0.f, 0.f, 0.f, 0.f};
    const short* vbase = vle + (size_t)n * L_ATT * 64;

#pragma unroll
    for (int q = 0; q < 9; ++q) {
        const int dy = q / 3 - 1, dx = q - (q / 3) * 3 - 1;
        const bool valid = ((unsigned)(ya + dy) < 48u) && ((unsigned)(xa + dx) < 48u);
        const short* ap = vbase + (size_t)(la + dy * 48 + dx) * 64 + quad * 8;
#pragma unroll
        for (int ks = 0; ks < 2; ++ks) {
            bh8 af = {0, 0, 0, 0, 0, 0, 0, 0};
            if (valid) af = *(const bh8*)(ap + ks * 32);
            bh8 bf = *(const bh8*)(wqp + ((size_t)q * 64 + t * 16 + col) * 64
                                   + ks * 32 + quad * 8);
            acc = __builtin_amdgcn_mfma_f32_16x16x32_bf16(af, bf, acc, 0, 0, 0);
        }
    }

    short* op = pcv + (size_t)n * L_ATT * 64;
    const int oc = t * 16 + col;
    const float bb = pbias[oc];
#pragma unroll
    for (int reg = 0; reg < 4; ++reg) {
        int l = l0 + quad * 4 + reg;
        op[(size_t)l * 64 + oc] = f2b(acc[reg] + bb);
    }
}

// ---------------------------------------------------------------------------
// res 1x1 conv, K=64: out = W.(t32 + pcv) + res_b — B fragment fused on the
// fly from fp32 t32 (attn) + bf16 pcv (posconv). Flat grid 1152, XCD-swizzled.
// ---------------------------------------------------------------------------
__global__ __launch_bounds__(256) void res_kernel(
    const float* __restrict__ t32, const short* __restrict__ pcv,
    const short* __restrict__ reswb, const float* __restrict__ res_b,
    float* __restrict__ out)
{
    const int g = blockIdx.x;              // 1152 = 8 * 144
    const int xcd = g & 7, rr = g >> 3;    // rr < 144
    const int y = rr & 7, grp = rr >> 3;   // grp < 18
    const int code = grp * 8 + xcd;        // < 144
    const int l0 = (code % 36) * 64, oc0 = y * 64, n = code / 36;

    const int lane = threadIdx.x & 63, wave = threadIdx.x >> 6;
    const int col = lane & 15, quad = lane >> 4;
    const int ocb = oc0 + wave * 16;

    f4 acc[4];
#pragma unroll
    for (int nt = 0; nt < 4; ++nt) acc[nt] = (f4){0.f, 0.f, 0.f, 0.f};

#pragma unroll
    for (int ks = 0; ks < 2; ++ks) {
        bh8 af = *(const bh8*)(reswb + (size_t)(ocb + col) * 64 + ks * 32 + quad * 8);
#pragma unroll
        for (int nt = 0; nt < 4; ++nt) {
            const size_t boff = ((size_t)n * L_ATT + l0 + nt * 16 + col) * 64
                              + ks * 32 + quad * 8;
            float4 ta = *(const float4*)(t32 + boff);
            float4 tb = *(const float4*)(t32 + boff + 4);
            bh8 pv = *(const bh8*)(pcv + boff);
            union { int i[4]; bh8 v; } pu;
            pu.i[0] = packhi(ta.x + b2f(pv[0]), ta.y + b2f(pv[1]));
            pu.i[1] = packhi(ta.z + b2f(pv[2]), ta.w + b2f(pv[3]));
            pu.i[2] = packhi(tb.x + b2f(pv[4]), tb.y + b2f(pv[5]));
            pu.i[3] = packhi(tb.z + b2f(pv[6]), tb.w + b2f(pv[7]));
            acc[nt] = __builtin_amdgcn_mfma_f32_16x16x32_bf16(af, pu.v, acc[nt], 0, 0, 0);
        }
    }

#pragma unroll
    for (int nt = 0; nt < 4; ++nt) {
        int l = l0 + nt * 16 + col;
#pragma unroll
        for (int reg = 0; reg < 4; ++reg) {
            int oc = ocb + quad * 4 + reg;
            out[((size_t)n * 512 + oc) * L_ATT + l] = acc[nt][reg] + res_b[oc];
        }
    }
}

// ---------------------------------------------------------------------------
extern "C" void kernel_launch(void* const* d_in, const int* in_sizes, int n_in,
                              void* d_out, int out_size, void* d_ws, size_t ws_size,
                              hipStream_t stream)
{
    const float* x      = (const float*)d_in[0];
    const float* qkv_w  = (const float*)d_in[1];
    const float* qkv_b  = (const float*)d_in[2];
    const float* pos_w  = (const float*)d_in[3];
    const float* pos_b  = (const float*)d_in[4];
    const float* res_w  = (const float*)d_in[5];
    const float* res_b  = (const float*)d_in[6];
    float* out = (float*)d_out;

    char* ws = (char*)d_ws;
    short* xt    = (short*)(ws);                    //  9,437,184 B: [4][2304][512]
    float* t32   = (float*)(ws);                    //  9,437,184 B: [4][2304][64] fp32 (xt dead after qkv)
    short* qt8   = (short*)(ws + 9437184);          //  1,179,648 B: [32][2304][8]
    short* kt8   = (short*)(ws + 10616832);         //  1,179,648 B: [32][2304][8]
    short* vt    = (short*)(ws + 11796480);         //  1,179,648 B: [32][8][2304]
    short* pcv   = (short*)(ws + 12976128);         //  1,179,648 B: [4][2304][64]
    short* wqb   = (short*)(ws + 14155776);         //    196,608 B: [192][512]
    short* reswb = (short*)(ws + 14352384);         //     65,536 B: [512][64]
    short* vle   = (short*)(ws + 14417920);         //  1,179,648 B: [4][2304][64]
    short* wqp   = (short*)(ws + 15597568);         //     73,728 B: [9][64][64]

    prep_kernel<<<1424, 256, 0, stream>>>(x, qkv_w, res_w, pos_w, xt, wqb, reswb, wqp);
    qkv_kernel<<<432, 256, 0, stream>>>(xt, wqb, qkv_b, qt8, kt8, vt, vle);
    attnpos_kernel<<<1152, 256, 0, stream>>>(qt8, kt8, vt, vle, wqp, pos_b, t32, pcv);
    res_kernel<<<1152, 256, 0, stream>>>(t32, pcv, reswb, res_b, out);
}

// Round 11
// 153.959 us; speedup vs baseline: 1.1774x; 1.0294x over previous
//
#include <hip/hip_runtime.h>

#define L_ATT 2304
// SCALE * log2(e): softmax via exp2 is mathematically identical
#define QSCALE_LOG2E 0.5100695712f

using bh8 = __attribute__((ext_vector_type(8))) short;  // 8 bf16 (4 VGPRs)
using f4  = __attribute__((ext_vector_type(4))) float;  // 4 fp32 acc

#if __has_builtin(__builtin_amdgcn_exp2f)
#define EXP2(x) __builtin_amdgcn_exp2f(x)
#else
#define EXP2(x) exp2f(x)
#endif

__device__ inline short f2b(float f) {   // RNE
    union { float f; unsigned u; } c; c.f = f;
    unsigned r = (c.u + 0x7FFFu + ((c.u >> 16) & 1u)) >> 16;
    return (short)r;
}
__device__ inline float b2f(short s) {
    union { unsigned u; float f; } c;
    c.u = ((unsigned)(unsigned short)s) << 16;
    return c.f;
}
// pack hi16(lo), hi16(hi) -> one dword (two bf16, truncation)
__device__ inline int packhi(float lo, float hi) {
    return (int)__builtin_amdgcn_perm(__float_as_uint(hi), __float_as_uint(lo), 0x07060302u);
}

// ---------------------------------------------------------------------------
// prep = wcvt (g<272) U xt transpose (g>=272). 1424 blocks x 256.
// ---------------------------------------------------------------------------
__global__ __launch_bounds__(256) void prep_kernel(
    const float* __restrict__ x, const float* __restrict__ qkv_w,
    const float* __restrict__ res_w, const float* __restrict__ pos_w,
    short* __restrict__ xt, short* __restrict__ wqb,
    short* __restrict__ reswb, short* __restrict__ wqp)
{
    __shared__ float s[64][68];
    const int g = blockIdx.x;
    if (g < 272) {
        int j = g * 256 + threadIdx.x;
        if (j < 24576) {
            float4 v = ((const float4*)qkv_w)[j];
            short4 o = { f2b(v.x), f2b(v.y), f2b(v.z), f2b(v.w) };
            *(short4*)(wqb + (size_t)j * 4) = o;
        } else if (j < 32768) {
            int idx = j - 24576;
            float4 v = ((const float4*)res_w)[idx];
            short4 o = { f2b(v.x), f2b(v.y), f2b(v.z), f2b(v.w) };
            *(short4*)(reswb + (size_t)idx * 4) = o;
        } else {
            int e = j - 32768;                 // e = q*4096 + (oc*64+ic)
            wqp[e] = f2b(pos_w[(size_t)(e & 4095) * 9 + (e >> 12)]);
        }
        return;
    }
    const int gg = g - 272;                    // 1152 = 36 * 8 * 4
    const int l0 = (gg % 36) * 64, k0 = ((gg / 36) & 7) * 64, n = gg / 288;
    const int tr = threadIdx.x >> 4, tc4 = (threadIdx.x & 15) * 4;
    const float* xp = x + ((size_t)n * 512 + k0) * L_ATT + l0;
#pragma unroll
    for (int r = 0; r < 4; ++r)
        *(float4*)&s[tr + r * 16][tc4] =
            *(const float4*)(xp + (size_t)(tr + r * 16) * L_ATT + tc4);
    __syncthreads();
    short* op = xt + ((size_t)n * L_ATT + l0) * 512 + k0;
#pragma unroll
    for (int r = 0; r < 4; ++r) {
        int l = tr + r * 16;
        short4 o = { f2b(s[tc4 + 0][l]), f2b(s[tc4 + 1][l]),
                     f2b(s[tc4 + 2][l]), f2b(s[tc4 + 3][l]) };
        *(short4*)(op + (size_t)l * 512 + tc4) = o;
    }
}

// ---------------------------------------------------------------------------
// qkv 1x1 conv as MFMA GEMM, 32-wide l-tiles (864 blocks = 13.5 waves/CU for
// latency hiding). Wave: 16 oc x 32 l, 16 k-steps x (1 A + 2 B) b128 loads.
// Flat grid 864 = 8 * 108, XCD-swizzled. Epilogue: q->qt8, k->kt8, v->vt+vle.
// ---------------------------------------------------------------------------
__global__ __launch_bounds__(256) void qkv_kernel(
    const short* __restrict__ xt, const short* __restrict__ wqb,
    const float* __restrict__ qkv_b, short* __restrict__ qt8,
    short* __restrict__ kt8, short* __restrict__ vt, short* __restrict__ vle)
{
    const int g = blockIdx.x;              // 864 = 8 * 108
    const int xcd = g & 7, rr = g >> 3;    // rr < 108
    const int y = rr % 3, grp = rr / 3;    // grp < 36
    const int code = grp * 8 + xcd;        // = ltile + 72*n, < 288
    const int l0 = (code % 72) * 32, oc0 = y * 64, n = code / 72;

    const int lane = threadIdx.x & 63, wave = threadIdx.x >> 6;
    const int col = lane & 15, quad = lane >> 4;
    const int ocb = oc0 + wave * 16;

    f4 acc[2];
    acc[0] = (f4){0.f, 0.f, 0.f, 0.f};
    acc[1] = (f4){0.f, 0.f, 0.f, 0.f};

    const short* arow = wqb + (size_t)(ocb + col) * 512 + quad * 8;
    const short* brow = xt + ((size_t)n * L_ATT + l0 + col) * 512 + quad * 8;

#pragma unroll 4
    for (int k0 = 0; k0 < 512; k0 += 32) {
        bh8 af = *(const bh8*)(arow + k0);
        bh8 b0 = *(const bh8*)(brow + k0);
        bh8 b1 = *(const bh8*)(brow + (size_t)16 * 512 + k0);
        acc[0] = __builtin_amdgcn_mfma_f32_16x16x32_bf16(af, b0, acc[0], 0, 0, 0);
        acc[1] = __builtin_amdgcn_mfma_f32_16x16x32_bf16(af, b1, acc[1], 0, 0, 0);
    }

    const int obase = ocb + quad * 4;       // multiple of 4; r0 never straddles
    const int h = obase / 24;
    const int r0 = obase - h * 24;
    const int slice = n * 8 + h;

#pragma unroll
    for (int nt = 0; nt < 2; ++nt) {
        int l = l0 + nt * 16 + col;
        float v[4];
#pragma unroll
        for (int reg = 0; reg < 4; ++reg) v[reg] = acc[nt][reg] + qkv_b[obase + reg];
        if (r0 < 8) {          // q: scale, pack short4
            short4 o = { f2b(v[0] * QSCALE_LOG2E), f2b(v[1] * QSCALE_LOG2E),
                         f2b(v[2] * QSCALE_LOG2E), f2b(v[3] * QSCALE_LOG2E) };
            *(short4*)(qt8 + ((size_t)slice * L_ATT + l) * 8 + r0) = o;
        } else if (r0 < 16) {  // k
            short4 o = { f2b(v[0]), f2b(v[1]), f2b(v[2]), f2b(v[3]) };
            *(short4*)(kt8 + ((size_t)slice * L_ATT + l) * 8 + (r0 - 8)) = o;
        } else {               // v
            short4 o = { f2b(v[0]), f2b(v[1]), f2b(v[2]), f2b(v[3]) };
            int d0 = r0 - 16;
#pragma unroll
            for (int reg = 0; reg < 4; ++reg)
                vt[((size_t)slice * 8 + d0 + reg) * L_ATT + l] = ((short*)&o)[reg];
            *(short4*)(vle + ((size_t)n * L_ATT + l) * 64 + h * 8 + d0) = o;
        }
    }
}

// ---------------------------------------------------------------------------
// attnpos: split-K(2) flash attention (g<1152) U 3x3 pos-conv (g>=1152).
// attn block = 128 queries x 1152 keys (18 tiles), LDS-shared K/V, writes
// PARTIAL numerator pnum + partial lsum pls (combine fused into res_kernel).
// 1728 blocks = 6.75/CU fills barrier-drain bubbles. h = g&7 XCD swizzle.
// ---------------------------------------------------------------------------
__global__ __launch_bounds__(256) void attnpos_kernel(
    const short* __restrict__ qt8, const short* __restrict__ kt8,
    const short* __restrict__ vt, const short* __restrict__ vle,
    const short* __restrict__ wqp, const float* __restrict__ pbias,
    float* __restrict__ pnum, float* __restrict__ pls, short* __restrict__ pcv)
{
    __shared__ short smem[2064];
    const int g = blockIdx.x;
    const int tid = threadIdx.x;
    const int lane = tid & 63, wave = tid >> 6;
    const int col = lane & 15, quad = lane >> 4;

    if (g < 1152) {                        // ---- attention half (split-K 2) ----
        const int h = g & 7, r = g >> 3;   // r < 144 = n(4) x qt(18) x half(2)
        const int n = r / 36;
        const int rem = r - n * 36;
        const int qt = rem >> 1, half = rem & 1;
        const int q0 = qt * 128;
        const int kbase = half * 1152;
        const int slice = n * 8 + h;

        const short* qs  = qt8 + (size_t)slice * L_ATT * 8;
        const short* ks8 = kt8 + (size_t)slice * L_ATT * 8;
        const short* vb  = vt  + (size_t)slice * 8 * L_ATT;

        if (tid < 16) smem[2048 + tid] = (tid < 8) ? (short)0x3F80 : (short)0;

        bh8 zero8 = {0, 0, 0, 0, 0, 0, 0, 0};
        bh8 qf[2];
#pragma unroll
        for (int f = 0; f < 2; ++f) {
            qf[f] = zero8;
            if (quad == 0)
                qf[f] = *(const bh8*)(qs + (size_t)(q0 + wave * 32 + f * 16 + col) * 8);
        }

        const int kxor = (quad == 0) ? 512 : 0;
        int kidx[4];
#pragma unroll
        for (int nt = 0; nt < 4; ++nt)
            kidx[nt] = (quad == 0) ? (nt * 16 + col) * 8 : 2056;
        const int vxor = (col < 8) ? 512 : 0;
        int vidx[2];
#pragma unroll
        for (int ks = 0; ks < 2; ++ks)
            vidx[ks] = (col < 8)
                     ? 1024 + col * 64 + ((ks * 32 + quad * 8 + col * 8) & 63)
                     : ((col == 8) ? 2048 : 2056);

        const int ksl = ((lane >> 5) & 1) * 32 + ((lane >> 2) & 1) * 16
                      + ((lane >> 3) & 3) * 4 + (lane & 3);
        const int vd = lane >> 3, vkc = (lane & 7) * 8;
        const int vsl = 1024 + vd * 64 + ((vkc + vd * 8) & 63);

        if (wave == 0)
            *(uint4*)&smem[ksl * 8] = *(const uint4*)(ks8 + (size_t)(kbase + lane) * 8);
        else if (wave == 1)
            *(uint4*)&smem[vsl] = *(const uint4*)(vb + (size_t)vd * L_ATT + kbase + vkc);
        __syncthreads();

        f4 oacc[2];
        oacc[0] = (f4){0.f, 0.f, 0.f, 0.f};
        oacc[1] = (f4){0.f, 0.f, 0.f, 0.f};

        int sofs = 512;
        for (int t = 0; t < 18; ++t) {
            // issue next tile's global loads NOW (t=17 overrun stays inside ws)
            uint4 dk, dv;
            if (wave == 0)
                dk = *(const uint4*)(ks8 + (size_t)(kbase + (t + 1) * 64 + lane) * 8);
            else if (wave == 1)
                dv = *(const uint4*)(vb + (size_t)vd * L_ATT + kbase + (t + 1) * 64 + vkc);

            bh8 kf[4], vf[2];
#pragma unroll
            for (int nt = 0; nt < 4; ++nt) kf[nt] = *(const bh8*)&smem[kidx[nt]];
#pragma unroll
            for (int ks = 0; ks < 2; ++ks) vf[ks] = *(const bh8*)&smem[vidx[ks]];

#pragma unroll
            for (int f = 0; f < 2; ++f) {
                f4 s[4];
#pragma unroll
                for (int nt = 0; nt < 4; ++nt) {
                    f4 z = (f4){0.f, 0.f, 0.f, 0.f};
                    s[nt] = __builtin_amdgcn_mfma_f32_16x16x32_bf16(kf[nt], qf[f], z, 0, 0, 0);
                }
                float e[4][4];
#pragma unroll
                for (int nt = 0; nt < 4; ++nt)
#pragma unroll
                    for (int reg = 0; reg < 4; ++reg)
                        e[nt][reg] = EXP2(s[nt][reg]);
#pragma unroll
                for (int ks = 0; ks < 2; ++ks) {
                    union { int i[4]; bh8 v; } pu;
                    pu.i[0] = packhi(e[2 * ks][0],     e[2 * ks][1]);
                    pu.i[1] = packhi(e[2 * ks][2],     e[2 * ks][3]);
                    pu.i[2] = packhi(e[2 * ks + 1][0], e[2 * ks + 1][1]);
                    pu.i[3] = packhi(e[2 * ks + 1][2], e[2 * ks + 1][3]);
                    oacc[f] = __builtin_amdgcn_mfma_f32_16x16x32_bf16(vf[ks], pu.v, oacc[f], 0, 0, 0);
                }
            }

            if (wave == 0)      *(uint4*)&smem[sofs + ksl * 8] = dk;
            else if (wave == 1) *(uint4*)&smem[sofs + vsl] = dv;

#pragma unroll
            for (int nt = 0; nt < 4; ++nt) kidx[nt] ^= kxor;
            vidx[0] ^= vxor; vidx[1] ^= vxor;
            sofs ^= 512;
            __syncthreads();
        }

        // partials: quad0 -> d0..3, quad1 -> d4..7, quad2/reg0 -> lsum
        const size_t prow = (size_t)(slice * 2 + half) * L_ATT;
#pragma unroll
        for (int f = 0; f < 2; ++f) {
            int qg = q0 + wave * 32 + f * 16 + col;
            if (quad < 2) {
                float4 o = { oacc[f][0], oacc[f][1], oacc[f][2], oacc[f][3] };
                *(float4*)(pnum + (prow + qg) * 8 + quad * 4) = o;
            } else if (quad == 2) {
                pls[prow + qg] = oacc[f][0];
            }
        }
        return;
    }

    // ---- posconv half ----
    const int gf = g - 1152;               // 576 = 144 * 4
    const int l0 = (gf % 144) * 16, n = gf / 144;
    const int t = wave;                    // oc-strip = wave id

    const int la = l0 + col;
    const int ya = la / 48, xa = la - ya * 48;

    f4 acc = (f4){0.f, 0.f, 0.f, 0.f};
    const short* vbase = vle + (size_t)n * L_ATT * 64;

#pragma unroll
    for (int q = 0; q < 9; ++q) {
        const int dy = q / 3 - 1, dx = q - (q / 3) * 3 - 1;
        const bool valid = ((unsigned)(ya + dy) < 48u) && ((unsigned)(xa + dx) < 48u);
        const short* ap = vbase + (size_t)(la + dy * 48 + dx) * 64 + quad * 8;
#pragma unroll
        for (int ks = 0; ks < 2; ++ks) {
            bh8 af = {0, 0, 0, 0, 0, 0, 0, 0};
            if (valid) af = *(const bh8*)(ap + ks * 32);
            bh8 bf = *(const bh8*)(wqp + ((size_t)q * 64 + t * 16 + col) * 64
                                   + ks * 32 + quad * 8);
            acc = __builtin_amdgcn_mfma_f32_16x16x32_bf16(af, bf, acc, 0, 0, 0);
        }
    }

    short* op = pcv + (size_t)n * L_ATT * 64;
    const int oc = t * 16 + col;
    const float bb = pbias[oc];
#pragma unroll
    for (int reg = 0; reg < 4; ++reg) {
        int l = l0 + quad * 4 + reg;
        op[(size_t)l * 64 + oc] = f2b(acc[reg] + bb);
    }
}

// ---------------------------------------------------------------------------
// res 1x1 conv, K=64: out = W.((num0+num1)/(ls0+ls1) + pcv) + res_b.
// Split-K combine fused into the B-fragment build: each lane's 8 channels
// live in ONE head (h = ks*4+quad), so lsum is 2 dword loads per fragment.
// Flat grid 1152, XCD-swizzled.
// ---------------------------------------------------------------------------
__global__ __launch_bounds__(256) void res_kernel(
    const float* __restrict__ pnum, const float* __restrict__ pls,
    const short* __restrict__ pcv, const short* __restrict__ reswb,
    const float* __restrict__ res_b, float* __restrict__ out)
{
    const int g = blockIdx.x;              // 1152 = 8 * 144
    const int xcd = g & 7, rr = g >> 3;    // rr < 144
    const int y = rr & 7, grp = rr >> 3;   // grp < 18
    const int code = grp * 8 + xcd;        // < 144
    const int l0 = (code % 36) * 64, oc0 = y * 64, n = code / 36;

    const int lane = threadIdx.x & 63, wave = threadIdx.x >> 6;
    const int col = lane & 15, quad = lane >> 4;
    const int ocb = oc0 + wave * 16;

    f4 acc[4];
#pragma unroll
    for (int nt = 0; nt < 4; ++nt) acc[nt] = (f4){0.f, 0.f, 0.f, 0.f};

#pragma unroll
    for (int ks = 0; ks < 2; ++ks) {
        bh8 af = *(const bh8*)(reswb + (size_t)(ocb + col) * 64 + ks * 32 + quad * 8);
        const int h = ks * 4 + quad;                 // head of this fragment
        const size_t p0 = (size_t)((n * 8 + h) * 2) * L_ATT;
        const size_t p1 = p0 + L_ATT;
#pragma unroll
        for (int nt = 0; nt < 4; ++nt) {
            const int l = l0 + nt * 16 + col;
            float4 a0 = *(const float4*)(pnum + (p0 + l) * 8);
            float4 a1 = *(const float4*)(pnum + (p0 + l) * 8 + 4);
            float4 b0 = *(const float4*)(pnum + (p1 + l) * 8);
            float4 b1 = *(const float4*)(pnum + (p1 + l) * 8 + 4);
            float inv = 1.0f / (pls[p0 + l] + pls[p1 + l]);
            bh8 pv = *(const bh8*)(pcv + ((size_t)n * L_ATT + l) * 64
                                   + ks * 32 + quad * 8);
            union { int i[4]; bh8 v; } pu;
            pu.i[0] = packhi((a0.x + b0.x) * inv + b2f(pv[0]),
                             (a0.y + b0.y) * inv + b2f(pv[1]));
            pu.i[1] = packhi((a0.z + b0.z) * inv + b2f(pv[2]),
                             (a0.w + b0.w) * inv + b2f(pv[3]));
            pu.i[2] = packhi((a1.x + b1.x) * inv + b2f(pv[4]),
                             (a1.y + b1.y) * inv + b2f(pv[5]));
            pu.i[3] = packhi((a1.z + b1.z) * inv + b2f(pv[6]),
                             (a1.w + b1.w) * inv + b2f(pv[7]));
            acc[nt] = __builtin_amdgcn_mfma_f32_16x16x32_bf16(af, pu.v, acc[nt], 0, 0, 0);
        }
    }

#pragma unroll
    for (int nt = 0; nt < 4; ++nt) {
        int l = l0 + nt * 16 + col;
#pragma unroll
        for (int reg = 0; reg < 4; ++reg) {
            int oc = ocb + quad * 4 + reg;
            out[((size_t)n * 512 + oc) * L_ATT + l] = acc[nt][reg] + res_b[oc];
        }
    }
}

// ---------------------------------------------------------------------------
extern "C" void kernel_launch(void* const* d_in, const int* in_sizes, int n_in,
                              void* d_out, int out_size, void* d_ws, size_t ws_size,
                              hipStream_t stream)
{
    const float* x      = (const float*)d_in[0];
    const float* qkv_w  = (const float*)d_in[1];
    const float* qkv_b  = (const float*)d_in[2];
    const float* pos_w  = (const float*)d_in[3];
    const float* pos_b  = (const float*)d_in[4];
    const float* res_w  = (const float*)d_in[5];
    const float* res_b  = (const float*)d_in[6];
    float* out = (float*)d_out;

    char* ws = (char*)d_ws;
    short* xt    = (short*)(ws);                    //  9,437,184 B: [4][2304][512]
    float* pnum  = (float*)(ws);                    //  4,718,592 B: [64][2304][8]  (xt dead after qkv)
    float* pls   = (float*)(ws + 4718592);          //    589,824 B: [64][2304]
    short* qt8   = (short*)(ws + 9437184);          //  1,179,648 B: [32][2304][8]
    short* kt8   = (short*)(ws + 10616832);         //  1,179,648 B: [32][2304][8]
    short* vt    = (short*)(ws + 11796480);         //  1,179,648 B: [32][8][2304]
    short* pcv   = (short*)(ws + 12976128);         //  1,179,648 B: [4][2304][64]
    short* wqb   = (short*)(ws + 14155776);         //    196,608 B: [192][512]
    short* reswb = (short*)(ws + 14352384);         //     65,536 B: [512][64]
    short* vle   = (short*)(ws + 14417920);         //  1,179,648 B: [4][2304][64]
    short* wqp   = (short*)(ws + 15597568);         //     73,728 B: [9][64][64]

    prep_kernel<<<1424, 256, 0, stream>>>(x, qkv_w, res_w, pos_w, xt, wqb, reswb, wqp);
    qkv_kernel<<<864, 256, 0, stream>>>(xt, wqb, qkv_b, qt8, kt8, vt, vle);
    attnpos_kernel<<<1728, 256, 0, stream>>>(qt8, kt8, vt, vle, wqp, pos_b, pnum, pls, pcv);
    res_kernel<<<1152, 256, 0, stream>>>(pnum, pls, pcv, reswb, res_b, out);
}